// Round 2
// baseline (4811.404 us; speedup 1.0000x reference)
//
#include <hip/hip_runtime.h>
#include <cstdint>
#include <cstddef>

typedef unsigned short u16;
typedef short bf16x8 __attribute__((ext_vector_type(8)));
typedef float f32x4 __attribute__((ext_vector_type(4)));

// ---------- bf16 helpers ----------
__device__ __forceinline__ float bf2f(u16 u) { return __uint_as_float(((unsigned)u) << 16); }
__device__ __forceinline__ u16 f2bf(float f) {
  unsigned i = __float_as_uint(f);
  i += 0x7fffu + ((i >> 16) & 1u);   // RNE
  return (u16)(i >> 16);
}
__device__ __forceinline__ unsigned packbf2(float lo, float hi) {
  return (unsigned)f2bf(lo) | ((unsigned)f2bf(hi) << 16);
}
__device__ __forceinline__ float lo16(unsigned u) { return __uint_as_float(u << 16); }
__device__ __forceinline__ float hi16(unsigned u) { return __uint_as_float(u & 0xffff0000u); }

// async global->LDS, 16 B per lane; LDS dest = wave-uniform base + lane*16
__device__ __forceinline__ void async_ld16(u16* lds, const u16* g) {
  __builtin_amdgcn_global_load_lds((const __attribute__((address_space(1))) void*)g,
                                   (__attribute__((address_space(3))) void*)lds, 16, 0, 0);
}

// ---------- fp32 -> bf16 cast, 8 elems/thread ----------
__global__ void k_cast8(const float4* __restrict__ x, uint4* __restrict__ y, int n8) {
  int i = blockIdx.x * 256 + threadIdx.x;
  if (i >= n8) return;
  float4 a = x[(size_t)i * 2], b = x[(size_t)i * 2 + 1];
  uint4 o;
  o.x = packbf2(a.x, a.y); o.y = packbf2(a.z, a.w);
  o.z = packbf2(b.x, b.y); o.w = packbf2(b.z, b.w);
  y[i] = o;
}

// =====================================================================
// Small-shape MFMA GEMM (unchanged from R1): 128x128 tile, 4 waves,
// 3-buffer counted-vmcnt pipeline. Used for M=512 shapes + K=320.
// OUTM: 0 bf16 store; 1 fp32 +=; 2 fp32 store.  ACT: 0 none,1 silu,2 gelu.
// =====================================================================
template<int ACT, int OUTM>
__global__ __launch_bounds__(256)
void gemm_mfma(const u16* __restrict__ A, const u16* __restrict__ W,
               const float* __restrict__ bias, void* __restrict__ Cp,
               int M, int N, int K, int ldc) {
  __shared__ u16 As[3][128 * 32];
  __shared__ u16 Bs[3][128 * 32];
  const int tid = threadIdx.x;
  const int wave = tid >> 6, lane = tid & 63;

  const int gx = gridDim.x;
  const int nwg = gx * (int)gridDim.y;
  const int flat = (int)blockIdx.y * gx + (int)blockIdx.x;
  const int xcd = flat & 7, lo = flat >> 3;
  const int q = nwg >> 3, r = nwg & 7;
  const int swz = (xcd < r ? xcd * (q + 1) : r * (q + 1) + (xcd - r) * q) + lo;
  const int bm = (swz / gx) * 128, bn = (swz % gx) * 128;

  const int wm = (wave & 1) * 64, wn = (wave >> 1) * 64;
  const int srow = tid >> 2, selem = (tid & 3) * 8;
  const u16* Ap0 = A + (size_t)(bm + srow) * K + selem;
  const u16* Ap1 = A + (size_t)(bm + srow + 64) * K + selem;
  const u16* Wp0 = W + (size_t)(bn + srow) * K + selem;
  const u16* Wp1 = W + (size_t)(bn + srow + 64) * K + selem;
  const int fr = lane & 15, fq = (lane >> 4) * 8;

  f32x4 acc[4][4];
#pragma unroll
  for (int i = 0; i < 4; ++i)
#pragma unroll
    for (int j = 0; j < 4; ++j) acc[i][j] = (f32x4){0.f, 0.f, 0.f, 0.f};

  const int nt = K >> 5;

  auto stage = [&](int buf, int k0) {
    u16* AsD = &As[buf][tid * 8];
    u16* BsD = &Bs[buf][tid * 8];
    async_ld16(AsD, Ap0 + k0);
    async_ld16(AsD + 2048, Ap1 + k0);
    async_ld16(BsD, Wp0 + k0);
    async_ld16(BsD + 2048, Wp1 + k0);
  };

  stage(0, 0);
  if (nt > 1) stage(1, 32);

  int bi = 0;
  for (int t = 0; t < nt; ++t) {
    if (t + 1 < nt) asm volatile("s_waitcnt vmcnt(4)" ::: "memory");
    else            asm volatile("s_waitcnt vmcnt(0)" ::: "memory");
    __builtin_amdgcn_s_barrier();
    if (t + 2 < nt) {
      int nb = bi + 2; if (nb >= 3) nb -= 3;
      stage(nb, (t + 2) << 5);
    }
    const u16* Asb = As[bi];
    const u16* Bsb = Bs[bi];
    bf16x8 af[4], bfv[4];
#pragma unroll
    for (int i = 0; i < 4; ++i)
      af[i] = *(const bf16x8*)&Asb[(wm + i * 16 + fr) * 32 + fq];
#pragma unroll
    for (int j = 0; j < 4; ++j)
      bfv[j] = *(const bf16x8*)&Bsb[(wn + j * 16 + fr) * 32 + fq];
#pragma unroll
    for (int i = 0; i < 4; ++i)
#pragma unroll
      for (int j = 0; j < 4; ++j)
        acc[i][j] = __builtin_amdgcn_mfma_f32_16x16x32_bf16(af[i], bfv[j], acc[i][j], 0, 0, 0);
    if (++bi == 3) bi = 0;
  }

  const int mr = bm + wm + (lane >> 4) * 4;
  const int nc = bn + wn + (lane & 15);
#pragma unroll
  for (int j = 0; j < 4; ++j) {
    int n = nc + j * 16;
    float bv = bias[n];
#pragma unroll
    for (int i = 0; i < 4; ++i) {
      int mbase = mr + i * 16;
#pragma unroll
      for (int r = 0; r < 4; ++r) {
        float v = acc[i][j][r] + bv;
        if (ACT == 1) v = v / (1.f + __expf(-v));
        else if (ACT == 2) v = 0.5f * v * (1.f + erff(v * 0.70710678118f));
        size_t off = (size_t)(mbase + r) * ldc + n;
        if (OUTM == 0) ((u16*)Cp)[off] = f2bf(v);
        else if (OUTM == 1) ((float*)Cp)[off] += v;
        else ((float*)Cp)[off] = v;
      }
    }
  }
}

// =====================================================================
// Big-shape MFMA GEMM: 256x256 tile, 8 waves (2Mx4N), BK=32,
// 4-deep LDS buffers (128 KiB), counted vmcnt (steady vmcnt(8), stage
// t+3 after the single per-K-step raw barrier), XOR chunk-swizzled LDS
// (conflict-free ds_read_b128: p = chunk ^ ((row>>1)&3), applied to BOTH
// the pre-swizzled global_load_lds source and the ds_read address),
// setprio(1) around the 32-MFMA cluster. Requires M%256==0, N%256==0,
// K%32==0, K>=128.
// =====================================================================
template<int ACT, int OUTM>
__global__ __launch_bounds__(512, 2)
void gemm_mfma256(const u16* __restrict__ A, const u16* __restrict__ W,
                  const float* __restrict__ bias, void* __restrict__ Cp,
                  int M, int N, int K, int ldc) {
  __shared__ u16 As[4][256 * 32];
  __shared__ u16 Bs[4][256 * 32];
  const int tid = threadIdx.x;
  const int wave = tid >> 6, lane = tid & 63;
  const int wave_m = wave >> 2, wave_n = wave & 3;      // 2 x 4
  const int WM = wave_m * 128, WN = wave_n * 64;

  // bijective XCD-chunk swizzle
  const int gx = gridDim.x;
  const int nwg = gx * (int)gridDim.y;
  const int flat = (int)blockIdx.y * gx + (int)blockIdx.x;
  const int xcd = flat & 7, lo = flat >> 3;
  const int q = nwg >> 3, r = nwg & 7;
  const int swz = (xcd < r ? xcd * (q + 1) : r * (q + 1) + (xcd - r) * q) + lo;
  const int bm = (swz / gx) * 256, bn = (swz % gx) * 256;

  // staging: thread t covers (row = q*128 + (t>>2), physical chunk t&3).
  // stored logical chunk l = (t&3) ^ ((row>>1)&3) = (t&3) ^ ((t>>3)&3)
  const int srow = tid >> 2;
  const int sl = ((tid & 3) ^ ((tid >> 3) & 3)) * 8;   // logical k-offset (elems)
  const u16* Ap0 = A + (size_t)(bm + srow) * K + sl;
  const u16* Ap1 = A + (size_t)(bm + 128 + srow) * K + sl;
  const u16* Wp0 = W + (size_t)(bn + srow) * K + sl;
  const u16* Wp1 = W + (size_t)(bn + 128 + srow) * K + sl;

  // fragment read addressing (swizzle-aware)
  const int fr = lane & 15;
  const int pA = (((lane >> 4) ^ ((fr >> 1) & 3))) * 8; // physical chunk offset (elems)
  const int aoff = (WM + fr) * 32 + pA;                  // + i*512 per M_rep
  const int boff = (WN + fr) * 32 + pA;                  // + j*512 per N_rep

  f32x4 acc[8][4];
#pragma unroll
  for (int i = 0; i < 8; ++i)
#pragma unroll
    for (int j = 0; j < 4; ++j) acc[i][j] = (f32x4){0.f, 0.f, 0.f, 0.f};

  const int nt = K >> 5;

  auto stage = [&](int buf, int k0) {
    u16* AsD = &As[buf][tid * 8];
    u16* BsD = &Bs[buf][tid * 8];
    async_ld16(AsD, Ap0 + k0);
    async_ld16(AsD + 4096, Ap1 + k0);
    async_ld16(BsD, Wp0 + k0);
    async_ld16(BsD + 4096, Wp1 + k0);
  };

  // prologue: fill all 4 buffers
#pragma unroll 1
  for (int s = 0; s < 4 && s < nt; ++s) stage(s, s << 5);

#pragma unroll 1
  for (int t = 0; t < nt; ++t) {
    // wait until only `infl` tiles (4 loads each, FIFO retire) outstanding
    int infl = (t == 0) ? 3 : 2;
    int rem = nt - 1 - t; if (infl > rem) infl = rem;
    if (infl >= 3)      asm volatile("s_waitcnt vmcnt(12)" ::: "memory");
    else if (infl == 2) asm volatile("s_waitcnt vmcnt(8)" ::: "memory");
    else if (infl == 1) asm volatile("s_waitcnt vmcnt(4)" ::: "memory");
    else                asm volatile("s_waitcnt vmcnt(0)" ::: "memory");
    __builtin_amdgcn_sched_barrier(0);
    __builtin_amdgcn_s_barrier();
    __builtin_amdgcn_sched_barrier(0);
    // buffer (t+3)&3 == (t-1)&3 was fully consumed before the barrier above
    if (t >= 1 && t + 3 < nt) stage((t + 3) & 3, (t + 3) << 5);

    const u16* Asb = As[t & 3];
    const u16* Bsb = Bs[t & 3];
    bf16x8 af[8], bfv[4];
#pragma unroll
    for (int i = 0; i < 8; ++i)
      af[i] = *(const bf16x8*)&Asb[aoff + i * 512];
#pragma unroll
    for (int j = 0; j < 4; ++j)
      bfv[j] = *(const bf16x8*)&Bsb[boff + j * 512];
    __builtin_amdgcn_s_setprio(1);
#pragma unroll
    for (int i = 0; i < 8; ++i)
#pragma unroll
      for (int j = 0; j < 4; ++j)
        acc[i][j] = __builtin_amdgcn_mfma_f32_16x16x32_bf16(af[i], bfv[j], acc[i][j], 0, 0, 0);
    __builtin_amdgcn_s_setprio(0);
  }

  // C/D: row=(lane>>4)*4+reg, col=lane&15
  const int mr = bm + WM + (lane >> 4) * 4;
  const int nc = bn + WN + fr;
#pragma unroll
  for (int j = 0; j < 4; ++j) {
    int n = nc + j * 16;
    float bv = bias[n];
#pragma unroll
    for (int i = 0; i < 8; ++i) {
      int mbase = mr + i * 16;
#pragma unroll
      for (int rr = 0; rr < 4; ++rr) {
        float v = acc[i][j][rr] + bv;
        if (ACT == 1) v = v / (1.f + __expf(-v));
        else if (ACT == 2) v = 0.5f * v * (1.f + erff(v * 0.70710678118f));
        size_t off = (size_t)(mbase + rr) * ldc + n;
        if (OUTM == 0) ((u16*)Cp)[off] = f2bf(v);
        else if (OUTM == 1) ((float*)Cp)[off] += v;
        else ((float*)Cp)[off] = v;
      }
    }
  }
}

// ---------- LayerNorm over D=512: fp32 in, fp32 w/b, bf16 out ----------
__global__ __launch_bounds__(256)
void k_layernorm(const float* __restrict__ X, const float* __restrict__ w,
                 const float* __restrict__ b, u16* __restrict__ Y) {
  int row = blockIdx.x, tid = threadIdx.x;
  const float* x = X + (size_t)row * 512;
  float v0 = x[tid], v1 = x[tid + 256];
  __shared__ float red[4];
  float s = v0 + v1;
  for (int o = 32; o; o >>= 1) s += __shfl_down(s, o, 64);
  if ((tid & 63) == 0) red[tid >> 6] = s;
  __syncthreads();
  if (tid == 0) red[0] = (red[0] + red[1] + red[2] + red[3]) * (1.f / 512.f);
  __syncthreads();
  float mean = red[0];
  __syncthreads();
  float d0 = v0 - mean, d1 = v1 - mean;
  float q = d0 * d0 + d1 * d1;
  for (int o = 32; o; o >>= 1) q += __shfl_down(q, o, 64);
  if ((tid & 63) == 0) red[tid >> 6] = q;
  __syncthreads();
  if (tid == 0) red[0] = (red[0] + red[1] + red[2] + red[3]) * (1.f / 512.f);
  __syncthreads();
  float rstd = rsqrtf(red[0] + 1e-5f);
  size_t o0 = (size_t)row * 512 + tid;
  Y[o0] = f2bf(d0 * rstd * w[tid] + b[tid]);
  Y[o0 + 256] = f2bf(d1 * rstd * w[tid + 256] + b[tid + 256]);
}

// ---------- condition input gather (fp32 tables -> bf16, padded to 320) ----------
__global__ void k_cond_gather(const int* __restrict__ note_id, const int* __restrict__ phon_id,
                              const int* __restrict__ slur, const int* __restrict__ pp,
                              const float* __restrict__ note_emb, const float* __restrict__ phon_emb,
                              const float* __restrict__ slur_emb, const float* __restrict__ pp_emb,
                              u16* __restrict__ out) {
  int bt = blockIdx.x, t = threadIdx.x;  // block = 320
  u16 v = 0;
  if (t < 128) v = f2bf(note_emb[note_id[bt] * 128 + t]);
  else if (t < 256) v = f2bf(phon_emb[phon_id[bt] * 128 + (t - 128)]);
  else if (t < 272) {
    int sv = slur[bt]; sv = sv < 0 ? 0 : (sv > 1 ? 1 : sv);
    v = f2bf(slur_emb[sv * 16 + (t - 256)]);
  } else if (t < 304) v = f2bf(pp_emb[pp[bt] * 32 + (t - 272)]);
  out[bt * 320 + t] = v;
}

// pad+cast cond_w1 [256,304] fp32 -> [256,320] bf16
__global__ void k_pad_w(const float* __restrict__ w, u16* __restrict__ out) {
  int n = blockIdx.x, t = threadIdx.x;  // grid 256, block 320
  out[n * 320 + t] = (t < 304) ? f2bf(w[n * 304 + t]) : (u16)0;
}

// gather temb(bf16)[codes[...,0]] -> f_emb [32768,256] (uint4 = 8 bf16)
__global__ void k_femb(const int* __restrict__ codes, const uint4* __restrict__ emb,
                       uint4* __restrict__ out) {
  int i = blockIdx.x * 256 + threadIdx.x;  // < 32768*32
  int m = i >> 5, c = i & 31;
  out[i] = emb[(size_t)codes[m * 2] * 32 + c];
}

// pooled[bt,c] = mean_s f_emb[bt*64+s, c]
__global__ void k_pool(const u16* __restrict__ femb, u16* __restrict__ pooled) {
  int bt = blockIdx.x, c = threadIdx.x;  // block 256
  float s = 0.f;
  for (int j = 0; j < 64; ++j) s += bf2f(femb[((size_t)bt * 64 + j) * 256 + c]);
  pooled[bt * 256 + c] = f2bf(s * (1.f / 64.f));
}

// step_in[bt] = [cond[bt] | (t==0 ? bos(fp32) : prevo[bt-1])]
__global__ void k_stepin(const u16* __restrict__ cond, const u16* __restrict__ prevo,
                         const float* __restrict__ bosf, u16* __restrict__ out) {
  int bt = blockIdx.x, t = threadIdx.x;  // block 512
  u16 v;
  if (t < 256) v = cond[bt * 256 + t];
  else {
    int tt = bt & 127;
    v = (tt == 0) ? f2bf(bosf[t - 256]) : prevo[(bt - 1) * 256 + (t - 256)];
  }
  out[bt * 512 + t] = v;
}

// ---------- ctx attention: one wave per (b,h,t), window 32 causal ----------
__global__ __launch_bounds__(64)
void k_ctx_attn(const u16* __restrict__ qkv, u16* __restrict__ out) {
  int t = blockIdx.x, h = blockIdx.y, b = blockIdx.z;
  int lane = threadIdx.x;
  int bt = b * 128 + t;
  float qd = bf2f(qkv[(size_t)bt * 1536 + h * 64 + lane]) * 0.125f;
  int klo = t - 31; if (klo < 0) klo = 0;
  int n = t - klo + 1;
  __shared__ float sc[32];
  for (int i = 0; i < n; ++i) {
    float p = qd * bf2f(qkv[((size_t)(b * 128 + klo + i)) * 1536 + 512 + h * 64 + lane]);
    for (int o = 32; o; o >>= 1) p += __shfl_xor(p, o, 64);
    if (lane == 0) sc[i] = p;
  }
  __syncthreads();
  float mx = -1e30f;
  for (int i = 0; i < n; ++i) mx = fmaxf(mx, sc[i]);
  float den = 0.f, acc = 0.f;
  for (int i = 0; i < n; ++i) {
    float p = __expf(sc[i] - mx);
    den += p;
    acc += p * bf2f(qkv[((size_t)(b * 128 + klo + i)) * 1536 + 1024 + h * 64 + lane]);
  }
  out[(size_t)bt * 512 + h * 64 + lane] = f2bf(acc / den);
}

// ---------- audio attention, MFMA: one wave per (seq,head); S=64, D=64, causal ----------
__global__ __launch_bounds__(128)
void k_aud_attn_mfma(const u16* __restrict__ qkv, u16* __restrict__ out) {
  constexpr int LP = 66;
  __shared__ u16 Pl[2][64 * LP];
  __shared__ u16 Vt[2][64 * LP];
  const int wave = threadIdx.x >> 6, lane = threadIdx.x & 63;
  const int id = blockIdx.x * 2 + wave;       // 0..4095
  const int seq = id >> 3, h = id & 7;
  const u16* Qb = qkv + (size_t)seq * 64 * 1536 + h * 64;
  const u16* Kb = Qb + 512;
  const u16* Vb = Qb + 1024;
  u16* Plw = Pl[wave];
  u16* Vtw = Vt[wave];
  const int fr = lane & 15, fq = (lane >> 4) * 8;

#pragma unroll
  for (int t = 0; t < 8; ++t) {
    int vr = (lane >> 3) + 8 * t, vc = (lane & 7) * 8;
    uint4 vv = *(const uint4*)(Vb + (size_t)vr * 1536 + vc);
    Vtw[(vc + 0) * LP + vr] = (u16)(vv.x & 0xffff);
    Vtw[(vc + 1) * LP + vr] = (u16)(vv.x >> 16);
    Vtw[(vc + 2) * LP + vr] = (u16)(vv.y & 0xffff);
    Vtw[(vc + 3) * LP + vr] = (u16)(vv.y >> 16);
    Vtw[(vc + 4) * LP + vr] = (u16)(vv.z & 0xffff);
    Vtw[(vc + 5) * LP + vr] = (u16)(vv.z >> 16);
    Vtw[(vc + 6) * LP + vr] = (u16)(vv.w & 0xffff);
    Vtw[(vc + 7) * LP + vr] = (u16)(vv.w >> 16);
  }

  bf16x8 aq[4][2], bk[4][2];
#pragma unroll
  for (int i = 0; i < 4; ++i)
#pragma unroll
    for (int c = 0; c < 2; ++c) {
      aq[i][c] = *(const bf16x8*)(Qb + (size_t)(i * 16 + fr) * 1536 + fq + 32 * c);
      bk[i][c] = *(const bf16x8*)(Kb + (size_t)(i * 16 + fr) * 1536 + fq + 32 * c);
    }
  f32x4 s[4][4];
#pragma unroll
  for (int i = 0; i < 4; ++i)
#pragma unroll
    for (int j = 0; j < 4; ++j) s[i][j] = (f32x4){0.f, 0.f, 0.f, 0.f};
#pragma unroll
  for (int c = 0; c < 2; ++c)
#pragma unroll
    for (int i = 0; i < 4; ++i)
#pragma unroll
      for (int j = 0; j < 4; ++j)
        s[i][j] = __builtin_amdgcn_mfma_f32_16x16x32_bf16(aq[i][c], bk[j][c], s[i][j], 0, 0, 0);

  const int qr = (lane >> 4) * 4;
#pragma unroll
  for (int i = 0; i < 4; ++i) {
#pragma unroll
    for (int r = 0; r < 4; ++r) {
      int row = 16 * i + qr + r;
      float mx = -1e30f;
      float vj[4];
#pragma unroll
      for (int j = 0; j < 4; ++j) {
        float v = s[i][j][r] * 0.125f;
        if (16 * j + fr > row) v = -1e30f;   // causal
        vj[j] = v;
        mx = fmaxf(mx, v);
      }
      for (int o = 8; o; o >>= 1) mx = fmaxf(mx, __shfl_xor(mx, o, 64));
      float den = 0.f;
#pragma unroll
      for (int j = 0; j < 4; ++j) { vj[j] = __expf(vj[j] - mx); den += vj[j]; }
      for (int o = 8; o; o >>= 1) den += __shfl_xor(den, o, 64);
      float inv = 1.f / den;
#pragma unroll
      for (int j = 0; j < 4; ++j)
        Plw[row * LP + 16 * j + fr] = f2bf(vj[j] * inv);
    }
  }
  __syncthreads();

  f32x4 o4[4][4];
#pragma unroll
  for (int i = 0; i < 4; ++i)
#pragma unroll
    for (int j = 0; j < 4; ++j) o4[i][j] = (f32x4){0.f, 0.f, 0.f, 0.f};
#pragma unroll
  for (int c = 0; c < 2; ++c) {
    bf16x8 ap[4], bv[4];
#pragma unroll
    for (int i = 0; i < 4; ++i)
      ap[i] = *(const bf16x8*)&Plw[(16 * i + fr) * LP + fq + 32 * c];
#pragma unroll
    for (int j = 0; j < 4; ++j)
      bv[j] = *(const bf16x8*)&Vtw[(16 * j + fr) * LP + fq + 32 * c];
#pragma unroll
    for (int i = 0; i < 4; ++i)
#pragma unroll
      for (int j = 0; j < 4; ++j)
        o4[i][j] = __builtin_amdgcn_mfma_f32_16x16x32_bf16(ap[i], bv[j], o4[i][j], 0, 0, 0);
  }
#pragma unroll
  for (int i = 0; i < 4; ++i)
#pragma unroll
    for (int r = 0; r < 4; ++r) {
      int row = 16 * i + qr + r;
      u16* ob = out + ((size_t)seq * 64 + row) * 512 + h * 64;
#pragma unroll
      for (int j = 0; j < 4; ++j) ob[16 * j + fr] = f2bf(o4[i][j][r]);
    }
}

// a[row,d] = (s==0 ? bos(fp32) : tok[row-1](bf16)) + frame_pos[s](fp32) + h[bt](fp32)
__global__ void k_abuild(const uint4* __restrict__ tok, const float4* __restrict__ bosf,
                         const float4* __restrict__ fpos, const float4* __restrict__ hstep,
                         float4* __restrict__ a) {
  size_t i = (size_t)blockIdx.x * 256 + threadIdx.x;  // < 32768*64
  int d8 = (int)(i & 63);
  size_t row = i >> 6;
  int s = (int)(row & 63);
  size_t bt = row >> 6;
  float t0, t1, t2, t3, t4, t5, t6, t7;
  if (s == 0) {
    float4 b0 = bosf[d8 * 2], b1 = bosf[d8 * 2 + 1];
    t0 = b0.x; t1 = b0.y; t2 = b0.z; t3 = b0.w;
    t4 = b1.x; t5 = b1.y; t6 = b1.z; t7 = b1.w;
  } else {
    uint4 tv = tok[(row - 1) * 64 + d8];
    t0 = lo16(tv.x); t1 = hi16(tv.x); t2 = lo16(tv.y); t3 = hi16(tv.y);
    t4 = lo16(tv.z); t5 = hi16(tv.z); t6 = lo16(tv.w); t7 = hi16(tv.w);
  }
  float4 f0 = fpos[(size_t)s * 128 + d8 * 2], f1 = fpos[(size_t)s * 128 + d8 * 2 + 1];
  float4 h0 = hstep[bt * 128 + d8 * 2], h1 = hstep[bt * 128 + d8 * 2 + 1];
  float4 o0, o1;
  o0.x = t0 + f0.x + h0.x; o0.y = t1 + f0.y + h0.y;
  o0.z = t2 + f0.z + h0.z; o0.w = t3 + f0.w + h0.w;
  o1.x = t4 + f1.x + h1.x; o1.y = t5 + f1.y + h1.y;
  o1.z = t6 + f1.z + h1.z; o1.w = t7 + f1.w + h1.w;
  a[i * 2] = o0; a[i * 2 + 1] = o1;
}

// cat[m] = [ah[m] | tok[m]]  (uint4 = 8 bf16)
__global__ void k_cat(const uint4* __restrict__ ah, const uint4* __restrict__ tok,
                      uint4* __restrict__ out) {
  size_t i = (size_t)blockIdx.x * 256 + threadIdx.x;  // < 32768*128
  size_t m = i >> 7;
  int c = (int)(i & 127);
  out[i] = (c < 64) ? ah[m * 64 + c] : tok[m * 64 + (c - 64)];
}

// ---------- host side ----------
template<int ACT, int OUTM>
static inline void gemm(const u16* A, const u16* W, const float* bias, void* C,
                        int M, int N, int K, int ldc, hipStream_t s) {
  gemm_mfma<ACT, OUTM><<<dim3(N / 128, M / 128), 256, 0, s>>>(A, W, bias, C, M, N, K, ldc);
}

template<int ACT, int OUTM>
static inline void gemmBig(const u16* A, const u16* W, const float* bias, void* C,
                           int M, int N, int K, int ldc, hipStream_t s) {
  gemm_mfma256<ACT, OUTM><<<dim3(N / 256, M / 256), 512, 0, s>>>(A, W, bias, C, M, N, K, ldc);
}

static inline void cast_bf16(const float* x, u16* y, size_t n, hipStream_t s) {
  int n8 = (int)(n / 8);
  k_cast8<<<(n8 + 255) / 256, 256, 0, s>>>((const float4*)x, (uint4*)y, n8);
}

extern "C" void kernel_launch(void* const* d_in, const int* in_sizes, int n_in,
                              void* d_out, int out_size, void* d_ws, size_t ws_size,
                              hipStream_t stream) {
  const int* codes    = (const int*)d_in[0];
  const int* note_id  = (const int*)d_in[1];
  const int* phon_id  = (const int*)d_in[2];
  const int* slur     = (const int*)d_in[3];
  const int* pprog    = (const int*)d_in[4];
  const float* note_emb = (const float*)d_in[5];
  const float* phon_emb = (const float*)d_in[6];
  const float* slur_emb = (const float*)d_in[7];
  const float* pp_emb   = (const float*)d_in[8];
  const float* cond_w1  = (const float*)d_in[9];
  const float* cond_b1  = (const float*)d_in[10];
  const float* cond_w2  = (const float*)d_in[11];
  const float* cond_b2  = (const float*)d_in[12];
  const float* tok_emb  = (const float*)d_in[13];
  const float* prev_w1  = (const float*)d_in[14];
  const float* prev_b1  = (const float*)d_in[15];
  const float* prev_w2  = (const float*)d_in[16];
  const float* prev_b2  = (const float*)d_in[17];
  const float* bos_step = (const float*)d_in[18];
  const float* step_w1  = (const float*)d_in[19];
  const float* step_b1  = (const float*)d_in[20];
  const float* step_w2  = (const float*)d_in[21];
  const float* step_b2  = (const float*)d_in[22];
  const float* audio_in_w = (const float*)d_in[23];
  const float* audio_in_b = (const float*)d_in[24];
  const float* audio_bos  = (const float*)d_in[25];
  const float* frame_pos  = (const float*)d_in[26];
  const float* first_w  = (const float*)d_in[27];
  const float* first_b  = (const float*)d_in[28];
  const float* resc_w1  = (const float*)d_in[29];
  const float* resc_b1  = (const float*)d_in[30];
  const float* resc_w2  = (const float*)d_in[31];
  const float* resc_b2  = (const float*)d_in[32];
  const float* res_w    = (const float*)d_in[33];
  const float* res_b    = (const float*)d_in[34];
  const float* ctx_w[12]; for (int i = 0; i < 12; ++i) ctx_w[i] = (const float*)d_in[35 + i];
  const float* aud_w[12]; for (int i = 0; i < 12; ++i) aud_w[i] = (const float*)d_in[47 + i];

  // workspace layout (deterministic every call)
  char* p = (char*)d_ws;
  auto alloc = [&](size_t b) { char* r = p; p += (b + 255) & ~(size_t)255; return r; };
  float* A_res = (float*)alloc(32768ull * 512 * 4);   // audio residual stream (fp32)
  u16* T_tok  = (u16*)alloc(32768ull * 512 * 2);      // tok (later reused for rh)
  u16* LNb    = (u16*)alloc(32768ull * 512 * 2);      // ln out / ah bf16
  u16* AOb    = (u16*)alloc(32768ull * 512 * 2);      // attn out / resc mid
  u16* QF     = (u16*)alloc(32768ull * 2048 * 2);     // qkv / ffn-mid / cat
  u16* f_emb  = (u16*)alloc(32768ull * 256 * 2);
  u16* temb   = (u16*)alloc(1024ull * 256 * 2);       // token_emb bf16
  u16* cond_in = (u16*)alloc(512ull * 320 * 2);
  u16* cw1p   = (u16*)alloc(256ull * 320 * 2);
  u16* cw2    = (u16*)alloc(256ull * 256 * 2);
  u16* pw1    = (u16*)alloc(256ull * 256 * 2);
  u16* pw2    = (u16*)alloc(256ull * 256 * 2);
  u16* sw1    = (u16*)alloc(512ull * 512 * 2);
  u16* sw2    = (u16*)alloc(512ull * 512 * 2);
  u16* ainw   = (u16*)alloc(512ull * 256 * 2);
  u16* fw     = (u16*)alloc(1024ull * 512 * 2);
  u16* rw1    = (u16*)alloc(512ull * 1024 * 2);
  u16* rw2    = (u16*)alloc(512ull * 512 * 2);
  u16* resw   = (u16*)alloc(1024ull * 512 * 2);
  u16* cxin   = (u16*)alloc(4ull * 1536 * 512 * 2);
  u16* cxout  = (u16*)alloc(4ull * 512 * 512 * 2);
  u16* cxf1   = (u16*)alloc(4ull * 2048 * 512 * 2);
  u16* cxf2   = (u16*)alloc(4ull * 512 * 2048 * 2);
  u16* adin   = (u16*)alloc(6ull * 1536 * 512 * 2);
  u16* adout  = (u16*)alloc(6ull * 512 * 512 * 2);
  u16* adf1   = (u16*)alloc(6ull * 2048 * 512 * 2);
  u16* adf2   = (u16*)alloc(6ull * 512 * 2048 * 2);
  u16* cond_h = (u16*)alloc(512ull * 256 * 2);
  u16* condv  = (u16*)alloc(512ull * 256 * 2);
  u16* pooled = (u16*)alloc(512ull * 256 * 2);
  u16* prevh  = (u16*)alloc(512ull * 256 * 2);
  u16* prevo  = (u16*)alloc(512ull * 256 * 2);
  u16* stepin = (u16*)alloc(512ull * 512 * 2);
  u16* hmid   = (u16*)alloc(512ull * 512 * 2);
  float* hstep = (float*)alloc(512ull * 512 * 4);     // ctx residual stream (fp32)

  // ---- weight fp32 -> bf16 conversions ----
  k_pad_w<<<256, 320, 0, stream>>>(cond_w1, cw1p);
  cast_bf16(cond_w2, cw2, 256ull * 256, stream);
  cast_bf16(prev_w1, pw1, 256ull * 256, stream);
  cast_bf16(prev_w2, pw2, 256ull * 256, stream);
  cast_bf16(step_w1, sw1, 512ull * 512, stream);
  cast_bf16(step_w2, sw2, 512ull * 512, stream);
  cast_bf16(tok_emb, temb, 1024ull * 256, stream);
  cast_bf16(audio_in_w, ainw, 512ull * 256, stream);
  cast_bf16(first_w, fw, 1024ull * 512, stream);
  cast_bf16(resc_w1, rw1, 512ull * 1024, stream);
  cast_bf16(resc_w2, rw2, 512ull * 512, stream);
  cast_bf16(res_w, resw, 1024ull * 512, stream);
  cast_bf16(ctx_w[2], cxin, 4ull * 1536 * 512, stream);
  cast_bf16(ctx_w[4], cxout, 4ull * 512 * 512, stream);
  cast_bf16(ctx_w[8], cxf1, 4ull * 2048 * 512, stream);
  cast_bf16(ctx_w[10], cxf2, 4ull * 512 * 2048, stream);
  cast_bf16(aud_w[2], adin, 6ull * 1536 * 512, stream);
  cast_bf16(aud_w[4], adout, 6ull * 512 * 512, stream);
  cast_bf16(aud_w[8], adf1, 6ull * 2048 * 512, stream);
  cast_bf16(aud_w[10], adf2, 6ull * 512 * 2048, stream);

  // ---- cond / prev / step ----
  k_cond_gather<<<512, 320, 0, stream>>>(note_id, phon_id, slur, pprog,
                                         note_emb, phon_emb, slur_emb, pp_emb, cond_in);
  k_femb<<<4096, 256, 0, stream>>>(codes, (const uint4*)temb, (uint4*)f_emb);
  k_pool<<<512, 256, 0, stream>>>(f_emb, pooled);
  gemm<1, 0>(cond_in, cw1p, cond_b1, cond_h, 512, 256, 320, 256, stream);
  gemm<0, 0>(cond_h, cw2, cond_b2, condv, 512, 256, 256, 256, stream);
  gemm<1, 0>(pooled, pw1, prev_b1, prevh, 512, 256, 256, 256, stream);
  gemm<0, 0>(prevh, pw2, prev_b2, prevo, 512, 256, 256, 256, stream);
  k_stepin<<<512, 512, 0, stream>>>(condv, prevo, bos_step, stepin);
  gemm<1, 0>(stepin, sw1, step_b1, hmid, 512, 512, 512, 512, stream);
  gemm<0, 2>(hmid, sw2, step_b2, hstep, 512, 512, 512, 512, stream);

  // ---- context transformer (T=128, win=32) ----
  for (int l = 0; l < 4; ++l) {
    k_layernorm<<<512, 256, 0, stream>>>(hstep, ctx_w[0] + l * 512, ctx_w[1] + l * 512, LNb);
    gemm<0, 0>(LNb, cxin + (size_t)l * 1536 * 512, ctx_w[3] + l * 1536, QF, 512, 1536, 512, 1536, stream);
    k_ctx_attn<<<dim3(128, 8, 4), 64, 0, stream>>>(QF, AOb);
    gemm<0, 1>(AOb, cxout + (size_t)l * 512 * 512, ctx_w[5] + l * 512, hstep, 512, 512, 512, 512, stream);
    k_layernorm<<<512, 256, 0, stream>>>(hstep, ctx_w[6] + l * 512, ctx_w[7] + l * 512, LNb);
    gemm<2, 0>(LNb, cxf1 + (size_t)l * 2048 * 512, ctx_w[9] + l * 2048, QF, 512, 2048, 512, 2048, stream);
    gemm<0, 1>(QF, cxf2 + (size_t)l * 512 * 2048, ctx_w[11] + l * 512, hstep, 512, 512, 2048, 512, stream);
  }

  // ---- audio decoder ----
  gemmBig<0, 0>(f_emb, ainw, audio_in_b, T_tok, 32768, 512, 256, 512, stream);
  k_abuild<<<8192, 256, 0, stream>>>((const uint4*)T_tok, (const float4*)audio_bos,
                                     (const float4*)frame_pos, (const float4*)hstep, (float4*)A_res);
  for (int l = 0; l < 6; ++l) {
    k_layernorm<<<32768, 256, 0, stream>>>(A_res, aud_w[0] + l * 512, aud_w[1] + l * 512, LNb);
    gemmBig<0, 0>(LNb, adin + (size_t)l * 1536 * 512, aud_w[3] + l * 1536, QF, 32768, 1536, 512, 1536, stream);
    k_aud_attn_mfma<<<2048, 128, 0, stream>>>(QF, AOb);
    gemmBig<0, 1>(AOb, adout + (size_t)l * 512 * 512, aud_w[5] + l * 512, A_res, 32768, 512, 512, 512, stream);
    k_layernorm<<<32768, 256, 0, stream>>>(A_res, aud_w[6] + l * 512, aud_w[7] + l * 512, LNb);
    gemmBig<2, 0>(LNb, adf1 + (size_t)l * 2048 * 512, aud_w[9] + l * 2048, QF, 32768, 2048, 512, 2048, stream);
    gemmBig<0, 1>(QF, adf2 + (size_t)l * 512 * 2048, aud_w[11] + l * 512, A_res, 32768, 512, 2048, 512, stream);
  }

  // ---- heads (fp32 output) ----
  {
    int n8 = 32768 * 512 / 8;
    k_cast8<<<(n8 + 255) / 256, 256, 0, stream>>>((const float4*)A_res, (uint4*)LNb, n8);
  }
  gemmBig<0, 2>(LNb, fw, first_b, (float*)d_out, 32768, 1024, 512, 2048, stream);          // k=0 slot
  k_cat<<<16384, 256, 0, stream>>>((const uint4*)LNb, (const uint4*)T_tok, (uint4*)QF);
  gemmBig<1, 0>(QF, rw1, resc_b1, AOb, 32768, 512, 1024, 512, stream);
  gemmBig<0, 0>(AOb, rw2, resc_b2, T_tok, 32768, 512, 512, 512, stream);                   // rh
  gemmBig<0, 2>(T_tok, resw, res_b, (float*)d_out + 1024, 32768, 1024, 512, 2048, stream); // k=1 slot
}

// Round 3
// 3621.867 us; speedup vs baseline: 1.3284x; 1.3284x over previous
//
#include <hip/hip_runtime.h>
#include <cstdint>
#include <cstddef>

typedef unsigned short u16;
typedef short bf16x8 __attribute__((ext_vector_type(8)));
typedef float f32x4 __attribute__((ext_vector_type(4)));

// ---------- bf16 helpers ----------
__device__ __forceinline__ float bf2f(u16 u) { return __uint_as_float(((unsigned)u) << 16); }
__device__ __forceinline__ u16 f2bf(float f) {
  unsigned i = __float_as_uint(f);
  i += 0x7fffu + ((i >> 16) & 1u);   // RNE
  return (u16)(i >> 16);
}
__device__ __forceinline__ unsigned packbf2(float lo, float hi) {
  return (unsigned)f2bf(lo) | ((unsigned)f2bf(hi) << 16);
}
__device__ __forceinline__ float lo16(unsigned u) { return __uint_as_float(u << 16); }
__device__ __forceinline__ float hi16(unsigned u) { return __uint_as_float(u & 0xffff0000u); }

// async global->LDS, 16 B per lane; LDS dest = wave-uniform base + lane*16
__device__ __forceinline__ void async_ld16(u16* lds, const u16* g) {
  __builtin_amdgcn_global_load_lds((const __attribute__((address_space(1))) void*)g,
                                   (__attribute__((address_space(3))) void*)lds, 16, 0, 0);
}

// ---------- fp32 -> bf16 cast, 8 elems/thread ----------
__global__ void k_cast8(const float4* __restrict__ x, uint4* __restrict__ y, int n8) {
  int i = blockIdx.x * 256 + threadIdx.x;
  if (i >= n8) return;
  float4 a = x[(size_t)i * 2], b = x[(size_t)i * 2 + 1];
  uint4 o;
  o.x = packbf2(a.x, a.y); o.y = packbf2(a.z, a.w);
  o.z = packbf2(b.x, b.y); o.w = packbf2(b.z, b.w);
  y[i] = o;
}

// =====================================================================
// MFMA GEMM:  C[m,n] = act( A[m,:]·W[n,:] + bias[n] )
// A: [M,K] bf16 row-major, W: [N,K] bf16 row-major. bias fp32.
// 128x128 tile, 4 waves, 4x4 16x16x32 frags, BK=32.
// K-loop: 3-buffer counted-vmcnt pipeline (proven R1 structure).
// Epilogue: coalesced LDS-staged C store — fragments go to the (free)
// 48 KiB staging LDS, then dense uint4/float4 row stores (full HBM
// lines) replace the old scattered 32B-segment stores that caused
// ~2.4x write amplification (R2 counters: WRITE 316MB vs 134MB useful).
// OUTM: 0 bf16 store; 1 fp32 +=; 2 fp32 store.  ACT: 0 none,1 silu,2 gelu.
// =====================================================================
template<int ACT, int OUTM>
__global__ __launch_bounds__(256)
void gemm_mfma(const u16* __restrict__ A, const u16* __restrict__ W,
               const float* __restrict__ bias, void* __restrict__ Cp,
               int M, int N, int K, int ldc) {
  __shared__ __align__(16) u16 SM[24576];   // 48 KiB: 3x8KiB A bufs + 3x8KiB B bufs
  const int tid = threadIdx.x;
  const int wave = tid >> 6, lane = tid & 63;

  // bijective XCD-chunk swizzle (m204)
  const int gx = gridDim.x;
  const int nwg = gx * (int)gridDim.y;
  const int flat = (int)blockIdx.y * gx + (int)blockIdx.x;
  const int xcd = flat & 7, lo = flat >> 3;
  const int q = nwg >> 3, r = nwg & 7;
  const int swz = (xcd < r ? xcd * (q + 1) : r * (q + 1) + (xcd - r) * q) + lo;
  const int bm = (swz / gx) * 128, bn = (swz % gx) * 128;

  const int wm = (wave & 1) * 64, wn = (wave >> 1) * 64;
  const int srow = tid >> 2, selem = (tid & 3) * 8;
  const u16* Ap0 = A + (size_t)(bm + srow) * K + selem;
  const u16* Ap1 = A + (size_t)(bm + srow + 64) * K + selem;
  const u16* Wp0 = W + (size_t)(bn + srow) * K + selem;
  const u16* Wp1 = W + (size_t)(bn + srow + 64) * K + selem;
  const int fr = lane & 15, fq = (lane >> 4) * 8;

  f32x4 acc[4][4];
#pragma unroll
  for (int i = 0; i < 4; ++i)
#pragma unroll
    for (int j = 0; j < 4; ++j) acc[i][j] = (f32x4){0.f, 0.f, 0.f, 0.f};

  const int nt = K >> 5;

  auto stage = [&](int buf, int k0) {
    u16* AsD = SM + buf * 4096 + tid * 8;
    u16* BsD = SM + 12288 + buf * 4096 + tid * 8;
    async_ld16(AsD, Ap0 + k0);
    async_ld16(AsD + 2048, Ap1 + k0);
    async_ld16(BsD, Wp0 + k0);
    async_ld16(BsD + 2048, Wp1 + k0);
  };

  stage(0, 0);
  if (nt > 1) stage(1, 32);

  int bi = 0;
  for (int t = 0; t < nt; ++t) {
    if (t + 1 < nt) asm volatile("s_waitcnt vmcnt(4)" ::: "memory");
    else            asm volatile("s_waitcnt vmcnt(0)" ::: "memory");
    __builtin_amdgcn_s_barrier();
    if (t + 2 < nt) {
      int nb = bi + 2; if (nb >= 3) nb -= 3;
      stage(nb, (t + 2) << 5);
    }
    const u16* Asb = SM + bi * 4096;
    const u16* Bsb = SM + 12288 + bi * 4096;
    bf16x8 af[4], bfv[4];
#pragma unroll
    for (int i = 0; i < 4; ++i)
      af[i] = *(const bf16x8*)&Asb[(wm + i * 16 + fr) * 32 + fq];
#pragma unroll
    for (int j = 0; j < 4; ++j)
      bfv[j] = *(const bf16x8*)&Bsb[(wn + j * 16 + fr) * 32 + fq];
#pragma unroll
    for (int i = 0; i < 4; ++i)
#pragma unroll
      for (int j = 0; j < 4; ++j)
        acc[i][j] = __builtin_amdgcn_mfma_f32_16x16x32_bf16(af[i], bfv[j], acc[i][j], 0, 0, 0);
    if (++bi == 3) bi = 0;
  }

  // ---------------- coalesced LDS-staged epilogue ----------------
  // C/D frag layout: row = wm + i*16 + (lane>>4)*4 + rr, col = wn + j*16 + fr
  __syncthreads();   // all waves done reading staging LDS
  const int lrow = (lane >> 4) * 4;
  const int colb = wn + fr;   // + j*16

  if (OUTM == 0) {
    u16* Ep = SM;   // [128][128] bf16 = 32 KiB
#pragma unroll
    for (int j = 0; j < 4; ++j) {
      float bv = bias[bn + colb + j * 16];
#pragma unroll
      for (int i = 0; i < 4; ++i)
#pragma unroll
        for (int rr = 0; rr < 4; ++rr) {
          float v = acc[i][j][rr] + bv;
          if (ACT == 1) v = v / (1.f + __expf(-v));
          else if (ACT == 2) v = 0.5f * v * (1.f + erff(v * 0.70710678118f));
          Ep[(wm + i * 16 + lrow + rr) * 128 + colb + j * 16] = f2bf(v);
        }
    }
    __syncthreads();
    // 128x128 bf16 = 2048 uint4; dense row stores (256B/row, full lines)
#pragma unroll
    for (int it = 0; it < 8; ++it) {
      int idx = it * 256 + tid;
      int row = idx >> 4, c = idx & 15;
      *(uint4*)((u16*)Cp + (size_t)(bm + row) * ldc + bn + c * 8) =
          ((const uint4*)Ep)[idx];
    }
  } else {
    float* Ep = (float*)SM;   // [64][128] fp32 = 32 KiB, two row-chunks
    float* Cf = (float*)Cp;
#pragma unroll
    for (int ch = 0; ch < 2; ++ch) {
      if ((wave & 1) == ch) {   // waves with wm == ch*64 own these rows
#pragma unroll
        for (int j = 0; j < 4; ++j) {
          float bv = bias[bn + colb + j * 16];
#pragma unroll
          for (int i = 0; i < 4; ++i)
#pragma unroll
            for (int rr = 0; rr < 4; ++rr) {
              float v = acc[i][j][rr] + bv;
              if (ACT == 1) v = v / (1.f + __expf(-v));
              else if (ACT == 2) v = 0.5f * v * (1.f + erff(v * 0.70710678118f));
              Ep[(i * 16 + lrow + rr) * 128 + colb + j * 16] = v;
            }
        }
      }
      __syncthreads();
      // 64x128 fp32 = 2048 float4; dense row stores / read-add-write
#pragma unroll
      for (int it = 0; it < 8; ++it) {
        int idx = it * 256 + tid;
        int row = idx >> 5, c4 = idx & 31;
        size_t g = (size_t)(bm + ch * 64 + row) * ldc + bn + c4 * 4;
        float4 sv = ((const float4*)Ep)[idx];
        if (OUTM == 1) {
          float4 od = *(const float4*)(Cf + g);
          sv.x += od.x; sv.y += od.y; sv.z += od.z; sv.w += od.w;
        }
        *(float4*)(Cf + g) = sv;
      }
      __syncthreads();
    }
  }
}

// ---------- LayerNorm over D=512: fp32 in, fp32 w/b, bf16 out ----------
__global__ __launch_bounds__(256)
void k_layernorm(const float* __restrict__ X, const float* __restrict__ w,
                 const float* __restrict__ b, u16* __restrict__ Y) {
  int row = blockIdx.x, tid = threadIdx.x;
  const float* x = X + (size_t)row * 512;
  float v0 = x[tid], v1 = x[tid + 256];
  __shared__ float red[4];
  float s = v0 + v1;
  for (int o = 32; o; o >>= 1) s += __shfl_down(s, o, 64);
  if ((tid & 63) == 0) red[tid >> 6] = s;
  __syncthreads();
  if (tid == 0) red[0] = (red[0] + red[1] + red[2] + red[3]) * (1.f / 512.f);
  __syncthreads();
  float mean = red[0];
  __syncthreads();
  float d0 = v0 - mean, d1 = v1 - mean;
  float q = d0 * d0 + d1 * d1;
  for (int o = 32; o; o >>= 1) q += __shfl_down(q, o, 64);
  if ((tid & 63) == 0) red[tid >> 6] = q;
  __syncthreads();
  if (tid == 0) red[0] = (red[0] + red[1] + red[2] + red[3]) * (1.f / 512.f);
  __syncthreads();
  float rstd = rsqrtf(red[0] + 1e-5f);
  size_t o0 = (size_t)row * 512 + tid;
  Y[o0] = f2bf(d0 * rstd * w[tid] + b[tid]);
  Y[o0 + 256] = f2bf(d1 * rstd * w[tid + 256] + b[tid + 256]);
}

// ---------- condition input gather (fp32 tables -> bf16, padded to 320) ----------
__global__ void k_cond_gather(const int* __restrict__ note_id, const int* __restrict__ phon_id,
                              const int* __restrict__ slur, const int* __restrict__ pp,
                              const float* __restrict__ note_emb, const float* __restrict__ phon_emb,
                              const float* __restrict__ slur_emb, const float* __restrict__ pp_emb,
                              u16* __restrict__ out) {
  int bt = blockIdx.x, t = threadIdx.x;  // block = 320
  u16 v = 0;
  if (t < 128) v = f2bf(note_emb[note_id[bt] * 128 + t]);
  else if (t < 256) v = f2bf(phon_emb[phon_id[bt] * 128 + (t - 128)]);
  else if (t < 272) {
    int sv = slur[bt]; sv = sv < 0 ? 0 : (sv > 1 ? 1 : sv);
    v = f2bf(slur_emb[sv * 16 + (t - 256)]);
  } else if (t < 304) v = f2bf(pp_emb[pp[bt] * 32 + (t - 272)]);
  out[bt * 320 + t] = v;
}

// pad+cast cond_w1 [256,304] fp32 -> [256,320] bf16
__global__ void k_pad_w(const float* __restrict__ w, u16* __restrict__ out) {
  int n = blockIdx.x, t = threadIdx.x;  // grid 256, block 320
  out[n * 320 + t] = (t < 304) ? f2bf(w[n * 304 + t]) : (u16)0;
}

// gather temb(bf16)[codes[...,0]] -> f_emb [32768,256] (uint4 = 8 bf16)
__global__ void k_femb(const int* __restrict__ codes, const uint4* __restrict__ emb,
                       uint4* __restrict__ out) {
  int i = blockIdx.x * 256 + threadIdx.x;  // < 32768*32
  int m = i >> 5, c = i & 31;
  out[i] = emb[(size_t)codes[m * 2] * 32 + c];
}

// pooled[bt,c] = mean_s f_emb[bt*64+s, c]
__global__ void k_pool(const u16* __restrict__ femb, u16* __restrict__ pooled) {
  int bt = blockIdx.x, c = threadIdx.x;  // block 256
  float s = 0.f;
  for (int j = 0; j < 64; ++j) s += bf2f(femb[((size_t)bt * 64 + j) * 256 + c]);
  pooled[bt * 256 + c] = f2bf(s * (1.f / 64.f));
}

// step_in[bt] = [cond[bt] | (t==0 ? bos(fp32) : prevo[bt-1])]
__global__ void k_stepin(const u16* __restrict__ cond, const u16* __restrict__ prevo,
                         const float* __restrict__ bosf, u16* __restrict__ out) {
  int bt = blockIdx.x, t = threadIdx.x;  // block 512
  u16 v;
  if (t < 256) v = cond[bt * 256 + t];
  else {
    int tt = bt & 127;
    v = (tt == 0) ? f2bf(bosf[t - 256]) : prevo[(bt - 1) * 256 + (t - 256)];
  }
  out[bt * 512 + t] = v;
}

// ---------- ctx attention: one wave per (b,h,t), window 32 causal ----------
__global__ __launch_bounds__(64)
void k_ctx_attn(const u16* __restrict__ qkv, u16* __restrict__ out) {
  int t = blockIdx.x, h = blockIdx.y, b = blockIdx.z;
  int lane = threadIdx.x;
  int bt = b * 128 + t;
  float qd = bf2f(qkv[(size_t)bt * 1536 + h * 64 + lane]) * 0.125f;
  int klo = t - 31; if (klo < 0) klo = 0;
  int n = t - klo + 1;
  __shared__ float sc[32];
  for (int i = 0; i < n; ++i) {
    float p = qd * bf2f(qkv[((size_t)(b * 128 + klo + i)) * 1536 + 512 + h * 64 + lane]);
    for (int o = 32; o; o >>= 1) p += __shfl_xor(p, o, 64);
    if (lane == 0) sc[i] = p;
  }
  __syncthreads();
  float mx = -1e30f;
  for (int i = 0; i < n; ++i) mx = fmaxf(mx, sc[i]);
  float den = 0.f, acc = 0.f;
  for (int i = 0; i < n; ++i) {
    float p = __expf(sc[i] - mx);
    den += p;
    acc += p * bf2f(qkv[((size_t)(b * 128 + klo + i)) * 1536 + 1024 + h * 64 + lane]);
  }
  out[(size_t)bt * 512 + h * 64 + lane] = f2bf(acc / den);
}

// ---------- audio attention, MFMA: one wave per (seq,head); S=64, D=64, causal ----------
__global__ __launch_bounds__(128)
void k_aud_attn_mfma(const u16* __restrict__ qkv, u16* __restrict__ out) {
  constexpr int LP = 66;
  __shared__ u16 Pl[2][64 * LP];
  __shared__ u16 Vt[2][64 * LP];
  const int wave = threadIdx.x >> 6, lane = threadIdx.x & 63;
  const int id = blockIdx.x * 2 + wave;       // 0..4095
  const int seq = id >> 3, h = id & 7;
  const u16* Qb = qkv + (size_t)seq * 64 * 1536 + h * 64;
  const u16* Kb = Qb + 512;
  const u16* Vb = Qb + 1024;
  u16* Plw = Pl[wave];
  u16* Vtw = Vt[wave];
  const int fr = lane & 15, fq = (lane >> 4) * 8;

#pragma unroll
  for (int t = 0; t < 8; ++t) {
    int vr = (lane >> 3) + 8 * t, vc = (lane & 7) * 8;
    uint4 vv = *(const uint4*)(Vb + (size_t)vr * 1536 + vc);
    Vtw[(vc + 0) * LP + vr] = (u16)(vv.x & 0xffff);
    Vtw[(vc + 1) * LP + vr] = (u16)(vv.x >> 16);
    Vtw[(vc + 2) * LP + vr] = (u16)(vv.y & 0xffff);
    Vtw[(vc + 3) * LP + vr] = (u16)(vv.y >> 16);
    Vtw[(vc + 4) * LP + vr] = (u16)(vv.z & 0xffff);
    Vtw[(vc + 5) * LP + vr] = (u16)(vv.z >> 16);
    Vtw[(vc + 6) * LP + vr] = (u16)(vv.w & 0xffff);
    Vtw[(vc + 7) * LP + vr] = (u16)(vv.w >> 16);
  }

  bf16x8 aq[4][2], bk[4][2];
#pragma unroll
  for (int i = 0; i < 4; ++i)
#pragma unroll
    for (int c = 0; c < 2; ++c) {
      aq[i][c] = *(const bf16x8*)(Qb + (size_t)(i * 16 + fr) * 1536 + fq + 32 * c);
      bk[i][c] = *(const bf16x8*)(Kb + (size_t)(i * 16 + fr) * 1536 + fq + 32 * c);
    }
  f32x4 s[4][4];
#pragma unroll
  for (int i = 0; i < 4; ++i)
#pragma unroll
    for (int j = 0; j < 4; ++j) s[i][j] = (f32x4){0.f, 0.f, 0.f, 0.f};
#pragma unroll
  for (int c = 0; c < 2; ++c)
#pragma unroll
    for (int i = 0; i < 4; ++i)
#pragma unroll
      for (int j = 0; j < 4; ++j)
        s[i][j] = __builtin_amdgcn_mfma_f32_16x16x32_bf16(aq[i][c], bk[j][c], s[i][j], 0, 0, 0);

  const int qr = (lane >> 4) * 4;
#pragma unroll
  for (int i = 0; i < 4; ++i) {
#pragma unroll
    for (int r = 0; r < 4; ++r) {
      int row = 16 * i + qr + r;
      float mx = -1e30f;
      float vj[4];
#pragma unroll
      for (int j = 0; j < 4; ++j) {
        float v = s[i][j][r] * 0.125f;
        if (16 * j + fr > row) v = -1e30f;   // causal
        vj[j] = v;
        mx = fmaxf(mx, v);
      }
      for (int o = 8; o; o >>= 1) mx = fmaxf(mx, __shfl_xor(mx, o, 64));
      float den = 0.f;
#pragma unroll
      for (int j = 0; j < 4; ++j) { vj[j] = __expf(vj[j] - mx); den += vj[j]; }
      for (int o = 8; o; o >>= 1) den += __shfl_xor(den, o, 64);
      float inv = 1.f / den;
#pragma unroll
      for (int j = 0; j < 4; ++j)
        Plw[row * LP + 16 * j + fr] = f2bf(vj[j] * inv);
    }
  }
  __syncthreads();

  f32x4 o4[4][4];
#pragma unroll
  for (int i = 0; i < 4; ++i)
#pragma unroll
    for (int j = 0; j < 4; ++j) o4[i][j] = (f32x4){0.f, 0.f, 0.f, 0.f};
#pragma unroll
  for (int c = 0; c < 2; ++c) {
    bf16x8 ap[4], bv[4];
#pragma unroll
    for (int i = 0; i < 4; ++i)
      ap[i] = *(const bf16x8*)&Plw[(16 * i + fr) * LP + fq + 32 * c];
#pragma unroll
    for (int j = 0; j < 4; ++j)
      bv[j] = *(const bf16x8*)&Vtw[(16 * j + fr) * LP + fq + 32 * c];
#pragma unroll
    for (int i = 0; i < 4; ++i)
#pragma unroll
      for (int j = 0; j < 4; ++j)
        o4[i][j] = __builtin_amdgcn_mfma_f32_16x16x32_bf16(ap[i], bv[j], o4[i][j], 0, 0, 0);
  }
#pragma unroll
  for (int i = 0; i < 4; ++i)
#pragma unroll
    for (int r = 0; r < 4; ++r) {
      int row = 16 * i + qr + r;
      u16* ob = out + ((size_t)seq * 64 + row) * 512 + h * 64;
#pragma unroll
      for (int j = 0; j < 4; ++j) ob[16 * j + fr] = f2bf(o4[i][j][r]);
    }
}

// a[row,d] = (s==0 ? bos(fp32) : tok[row-1](bf16)) + frame_pos[s](fp32) + h[bt](fp32)
__global__ void k_abuild(const uint4* __restrict__ tok, const float4* __restrict__ bosf,
                         const float4* __restrict__ fpos, const float4* __restrict__ hstep,
                         float4* __restrict__ a) {
  size_t i = (size_t)blockIdx.x * 256 + threadIdx.x;  // < 32768*64
  int d8 = (int)(i & 63);
  size_t row = i >> 6;
  int s = (int)(row & 63);
  size_t bt = row >> 6;
  float t0, t1, t2, t3, t4, t5, t6, t7;
  if (s == 0) {
    float4 b0 = bosf[d8 * 2], b1 = bosf[d8 * 2 + 1];
    t0 = b0.x; t1 = b0.y; t2 = b0.z; t3 = b0.w;
    t4 = b1.x; t5 = b1.y; t6 = b1.z; t7 = b1.w;
  } else {
    uint4 tv = tok[(row - 1) * 64 + d8];
    t0 = lo16(tv.x); t1 = hi16(tv.x); t2 = lo16(tv.y); t3 = hi16(tv.y);
    t4 = lo16(tv.z); t5 = hi16(tv.z); t6 = lo16(tv.w); t7 = hi16(tv.w);
  }
  float4 f0 = fpos[(size_t)s * 128 + d8 * 2], f1 = fpos[(size_t)s * 128 + d8 * 2 + 1];
  float4 h0 = hstep[bt * 128 + d8 * 2], h1 = hstep[bt * 128 + d8 * 2 + 1];
  float4 o0, o1;
  o0.x = t0 + f0.x + h0.x; o0.y = t1 + f0.y + h0.y;
  o0.z = t2 + f0.z + h0.z; o0.w = t3 + f0.w + h0.w;
  o1.x = t4 + f1.x + h1.x; o1.y = t5 + f1.y + h1.y;
  o1.z = t6 + f1.z + h1.z; o1.w = t7 + f1.w + h1.w;
  a[i * 2] = o0; a[i * 2 + 1] = o1;
}

// cat[m] = [ah[m] | tok[m]]  (uint4 = 8 bf16)
__global__ void k_cat(const uint4* __restrict__ ah, const uint4* __restrict__ tok,
                      uint4* __restrict__ out) {
  size_t i = (size_t)blockIdx.x * 256 + threadIdx.x;  // < 32768*128
  size_t m = i >> 7;
  int c = (int)(i & 127);
  out[i] = (c < 64) ? ah[m * 64 + c] : tok[m * 64 + (c - 64)];
}

// ---------- host side ----------
template<int ACT, int OUTM>
static inline void gemm(const u16* A, const u16* W, const float* bias, void* C,
                        int M, int N, int K, int ldc, hipStream_t s) {
  gemm_mfma<ACT, OUTM><<<dim3(N / 128, M / 128), 256, 0, s>>>(A, W, bias, C, M, N, K, ldc);
}

static inline void cast_bf16(const float* x, u16* y, size_t n, hipStream_t s) {
  int n8 = (int)(n / 8);
  k_cast8<<<(n8 + 255) / 256, 256, 0, s>>>((const float4*)x, (uint4*)y, n8);
}

extern "C" void kernel_launch(void* const* d_in, const int* in_sizes, int n_in,
                              void* d_out, int out_size, void* d_ws, size_t ws_size,
                              hipStream_t stream) {
  const int* codes    = (const int*)d_in[0];
  const int* note_id  = (const int*)d_in[1];
  const int* phon_id  = (const int*)d_in[2];
  const int* slur     = (const int*)d_in[3];
  const int* pprog    = (const int*)d_in[4];
  const float* note_emb = (const float*)d_in[5];
  const float* phon_emb = (const float*)d_in[6];
  const float* slur_emb = (const float*)d_in[7];
  const float* pp_emb   = (const float*)d_in[8];
  const float* cond_w1  = (const float*)d_in[9];
  const float* cond_b1  = (const float*)d_in[10];
  const float* cond_w2  = (const float*)d_in[11];
  const float* cond_b2  = (const float*)d_in[12];
  const float* tok_emb  = (const float*)d_in[13];
  const float* prev_w1  = (const float*)d_in[14];
  const float* prev_b1  = (const float*)d_in[15];
  const float* prev_w2  = (const float*)d_in[16];
  const float* prev_b2  = (const float*)d_in[17];
  const float* bos_step = (const float*)d_in[18];
  const float* step_w1  = (const float*)d_in[19];
  const float* step_b1  = (const float*)d_in[20];
  const float* step_w2  = (const float*)d_in[21];
  const float* step_b2  = (const float*)d_in[22];
  const float* audio_in_w = (const float*)d_in[23];
  const float* audio_in_b = (const float*)d_in[24];
  const float* audio_bos  = (const float*)d_in[25];
  const float* frame_pos  = (const float*)d_in[26];
  const float* first_w  = (const float*)d_in[27];
  const float* first_b  = (const float*)d_in[28];
  const float* resc_w1  = (const float*)d_in[29];
  const float* resc_b1  = (const float*)d_in[30];
  const float* resc_w2  = (const float*)d_in[31];
  const float* resc_b2  = (const float*)d_in[32];
  const float* res_w    = (const float*)d_in[33];
  const float* res_b    = (const float*)d_in[34];
  const float* ctx_w[12]; for (int i = 0; i < 12; ++i) ctx_w[i] = (const float*)d_in[35 + i];
  const float* aud_w[12]; for (int i = 0; i < 12; ++i) aud_w[i] = (const float*)d_in[47 + i];

  // workspace layout (deterministic every call)
  char* p = (char*)d_ws;
  auto alloc = [&](size_t b) { char* r = p; p += (b + 255) & ~(size_t)255; return r; };
  float* A_res = (float*)alloc(32768ull * 512 * 4);   // audio residual stream (fp32)
  u16* T_tok  = (u16*)alloc(32768ull * 512 * 2);      // tok (later reused for rh)
  u16* LNb    = (u16*)alloc(32768ull * 512 * 2);      // ln out / ah bf16
  u16* AOb    = (u16*)alloc(32768ull * 512 * 2);      // attn out / resc mid
  u16* QF     = (u16*)alloc(32768ull * 2048 * 2);     // qkv / ffn-mid / cat
  u16* f_emb  = (u16*)alloc(32768ull * 256 * 2);
  u16* temb   = (u16*)alloc(1024ull * 256 * 2);       // token_emb bf16
  u16* cond_in = (u16*)alloc(512ull * 320 * 2);
  u16* cw1p   = (u16*)alloc(256ull * 320 * 2);
  u16* cw2    = (u16*)alloc(256ull * 256 * 2);
  u16* pw1    = (u16*)alloc(256ull * 256 * 2);
  u16* pw2    = (u16*)alloc(256ull * 256 * 2);
  u16* sw1    = (u16*)alloc(512ull * 512 * 2);
  u16* sw2    = (u16*)alloc(512ull * 512 * 2);
  u16* ainw   = (u16*)alloc(512ull * 256 * 2);
  u16* fw     = (u16*)alloc(1024ull * 512 * 2);
  u16* rw1    = (u16*)alloc(512ull * 1024 * 2);
  u16* rw2    = (u16*)alloc(512ull * 512 * 2);
  u16* resw   = (u16*)alloc(1024ull * 512 * 2);
  u16* cxin   = (u16*)alloc(4ull * 1536 * 512 * 2);
  u16* cxout  = (u16*)alloc(4ull * 512 * 512 * 2);
  u16* cxf1   = (u16*)alloc(4ull * 2048 * 512 * 2);
  u16* cxf2   = (u16*)alloc(4ull * 512 * 2048 * 2);
  u16* adin   = (u16*)alloc(6ull * 1536 * 512 * 2);
  u16* adout  = (u16*)alloc(6ull * 512 * 512 * 2);
  u16* adf1   = (u16*)alloc(6ull * 2048 * 512 * 2);
  u16* adf2   = (u16*)alloc(6ull * 512 * 2048 * 2);
  u16* cond_h = (u16*)alloc(512ull * 256 * 2);
  u16* condv  = (u16*)alloc(512ull * 256 * 2);
  u16* pooled = (u16*)alloc(512ull * 256 * 2);
  u16* prevh  = (u16*)alloc(512ull * 256 * 2);
  u16* prevo  = (u16*)alloc(512ull * 256 * 2);
  u16* stepin = (u16*)alloc(512ull * 512 * 2);
  u16* hmid   = (u16*)alloc(512ull * 512 * 2);
  float* hstep = (float*)alloc(512ull * 512 * 4);     // ctx residual stream (fp32)

  // ---- weight fp32 -> bf16 conversions ----
  k_pad_w<<<256, 320, 0, stream>>>(cond_w1, cw1p);
  cast_bf16(cond_w2, cw2, 256ull * 256, stream);
  cast_bf16(prev_w1, pw1, 256ull * 256, stream);
  cast_bf16(prev_w2, pw2, 256ull * 256, stream);
  cast_bf16(step_w1, sw1, 512ull * 512, stream);
  cast_bf16(step_w2, sw2, 512ull * 512, stream);
  cast_bf16(tok_emb, temb, 1024ull * 256, stream);
  cast_bf16(audio_in_w, ainw, 512ull * 256, stream);
  cast_bf16(first_w, fw, 1024ull * 512, stream);
  cast_bf16(resc_w1, rw1, 512ull * 1024, stream);
  cast_bf16(resc_w2, rw2, 512ull * 512, stream);
  cast_bf16(res_w, resw, 1024ull * 512, stream);
  cast_bf16(ctx_w[2], cxin, 4ull * 1536 * 512, stream);
  cast_bf16(ctx_w[4], cxout, 4ull * 512 * 512, stream);
  cast_bf16(ctx_w[8], cxf1, 4ull * 2048 * 512, stream);
  cast_bf16(ctx_w[10], cxf2, 4ull * 512 * 2048, stream);
  cast_bf16(aud_w[2], adin, 6ull * 1536 * 512, stream);
  cast_bf16(aud_w[4], adout, 6ull * 512 * 512, stream);
  cast_bf16(aud_w[8], adf1, 6ull * 2048 * 512, stream);
  cast_bf16(aud_w[10], adf2, 6ull * 512 * 2048, stream);

  // ---- cond / prev / step ----
  k_cond_gather<<<512, 320, 0, stream>>>(note_id, phon_id, slur, pprog,
                                         note_emb, phon_emb, slur_emb, pp_emb, cond_in);
  k_femb<<<4096, 256, 0, stream>>>(codes, (const uint4*)temb, (uint4*)f_emb);
  k_pool<<<512, 256, 0, stream>>>(f_emb, pooled);
  gemm<1, 0>(cond_in, cw1p, cond_b1, cond_h, 512, 256, 320, 256, stream);
  gemm<0, 0>(cond_h, cw2, cond_b2, condv, 512, 256, 256, 256, stream);
  gemm<1, 0>(pooled, pw1, prev_b1, prevh, 512, 256, 256, 256, stream);
  gemm<0, 0>(prevh, pw2, prev_b2, prevo, 512, 256, 256, 256, stream);
  k_stepin<<<512, 512, 0, stream>>>(condv, prevo, bos_step, stepin);
  gemm<1, 0>(stepin, sw1, step_b1, hmid, 512, 512, 512, 512, stream);
  gemm<0, 2>(hmid, sw2, step_b2, hstep, 512, 512, 512, 512, stream);

  // ---- context transformer (T=128, win=32) ----
  for (int l = 0; l < 4; ++l) {
    k_layernorm<<<512, 256, 0, stream>>>(hstep, ctx_w[0] + l * 512, ctx_w[1] + l * 512, LNb);
    gemm<0, 0>(LNb, cxin + (size_t)l * 1536 * 512, ctx_w[3] + l * 1536, QF, 512, 1536, 512, 1536, stream);
    k_ctx_attn<<<dim3(128, 8, 4), 64, 0, stream>>>(QF, AOb);
    gemm<0, 1>(AOb, cxout + (size_t)l * 512 * 512, ctx_w[5] + l * 512, hstep, 512, 512, 512, 512, stream);
    k_layernorm<<<512, 256, 0, stream>>>(hstep, ctx_w[6] + l * 512, ctx_w[7] + l * 512, LNb);
    gemm<2, 0>(LNb, cxf1 + (size_t)l * 2048 * 512, ctx_w[9] + l * 2048, QF, 512, 2048, 512, 2048, stream);
    gemm<0, 1>(QF, cxf2 + (size_t)l * 512 * 2048, ctx_w[11] + l * 512, hstep, 512, 512, 2048, 512, stream);
  }

  // ---- audio decoder ----
  gemm<0, 0>(f_emb, ainw, audio_in_b, T_tok, 32768, 512, 256, 512, stream);
  k_abuild<<<8192, 256, 0, stream>>>((const uint4*)T_tok, (const float4*)audio_bos,
                                     (const float4*)frame_pos, (const float4*)hstep, (float4*)A_res);
  for (int l = 0; l < 6; ++l) {
    k_layernorm<<<32768, 256, 0, stream>>>(A_res, aud_w[0] + l * 512, aud_w[1] + l * 512, LNb);
    gemm<0, 0>(LNb, adin + (size_t)l * 1536 * 512, aud_w[3] + l * 1536, QF, 32768, 1536, 512, 1536, stream);
    k_aud_attn_mfma<<<2048, 128, 0, stream>>>(QF, AOb);
    gemm<0, 1>(AOb, adout + (size_t)l * 512 * 512, aud_w[5] + l * 512, A_res, 32768, 512, 512, 512, stream);
    k_layernorm<<<32768, 256, 0, stream>>>(A_res, aud_w[6] + l * 512, aud_w[7] + l * 512, LNb);
    gemm<2, 0>(LNb, adf1 + (size_t)l * 2048 * 512, aud_w[9] + l * 2048, QF, 32768, 2048, 512, 2048, stream);
    gemm<0, 1>(QF, adf2 + (size_t)l * 512 * 2048, aud_w[11] + l * 512, A_res, 32768, 512, 2048, 512, stream);
  }

  // ---- heads (fp32 output) ----
  {
    int n8 = 32768 * 512 / 8;
    k_cast8<<<(n8 + 255) / 256, 256, 0, stream>>>((const float4*)A_res, (uint4*)LNb, n8);
  }
  gemm<0, 2>(LNb, fw, first_b, (float*)d_out, 32768, 1024, 512, 2048, stream);          // k=0 slot
  k_cat<<<16384, 256, 0, stream>>>((const uint4*)LNb, (const uint4*)T_tok, (uint4*)QF);
  gemm<1, 0>(QF, rw1, resc_b1, AOb, 32768, 512, 1024, 512, stream);
  gemm<0, 0>(AOb, rw2, resc_b2, T_tok, 32768, 512, 512, 512, stream);                   // rh
  gemm<0, 2>(T_tok, resw, res_b, (float*)d_out + 1024, 32768, 1024, 512, 2048, stream); // k=1 slot
}

// Round 4
// 3600.692 us; speedup vs baseline: 1.3362x; 1.0059x over previous
//
#include <hip/hip_runtime.h>
#include <cstdint>
#include <cstddef>

typedef unsigned short u16;
typedef short bf16x8 __attribute__((ext_vector_type(8)));
typedef float f32x4 __attribute__((ext_vector_type(4)));

// ---------- bf16 helpers ----------
__device__ __forceinline__ float bf2f(u16 u) { return __uint_as_float(((unsigned)u) << 16); }
__device__ __forceinline__ u16 f2bf(float f) {
  unsigned i = __float_as_uint(f);
  i += 0x7fffu + ((i >> 16) & 1u);   // RNE
  return (u16)(i >> 16);
}
__device__ __forceinline__ unsigned packbf2(float lo, float hi) {
  return (unsigned)f2bf(lo) | ((unsigned)f2bf(hi) << 16);
}
__device__ __forceinline__ float lo16(unsigned u) { return __uint_as_float(u << 16); }
__device__ __forceinline__ float hi16(unsigned u) { return __uint_as_float(u & 0xffff0000u); }

// async global->LDS, 16 B per lane; LDS dest = wave-uniform base + lane*16
__device__ __forceinline__ void async_ld16(u16* lds, const u16* g) {
  __builtin_amdgcn_global_load_lds((const __attribute__((address_space(1))) void*)g,
                                   (__attribute__((address_space(3))) void*)lds, 16, 0, 0);
}

// fenced barrier: sched_barrier stops the compiler moving LDS ops across it
__device__ __forceinline__ void fbar() {
  __builtin_amdgcn_sched_barrier(0);
  __builtin_amdgcn_s_barrier();
  __builtin_amdgcn_sched_barrier(0);
}

// ---------- fp32 -> bf16 cast, 8 elems/thread ----------
__global__ void k_cast8(const float4* __restrict__ x, uint4* __restrict__ y, int n8) {
  int i = blockIdx.x * 256 + threadIdx.x;
  if (i >= n8) return;
  float4 a = x[(size_t)i * 2], b = x[(size_t)i * 2 + 1];
  uint4 o;
  o.x = packbf2(a.x, a.y); o.y = packbf2(a.z, a.w);
  o.z = packbf2(b.x, b.y); o.w = packbf2(b.z, b.w);
  y[i] = o;
}

// =====================================================================
// Small-shape MFMA GEMM (proven R3): 128x128 tile, 4 waves, BK=32,
// 3-buffer counted-vmcnt pipeline + coalesced LDS-staged epilogue.
// Used for M=512 shapes (ctx/cond/prev/step) incl. K=320.
// OUTM: 0 bf16 store; 1 fp32 +=; 2 fp32 store.  ACT: 0 none,1 silu,2 gelu.
// =====================================================================
template<int ACT, int OUTM>
__global__ __launch_bounds__(256)
void gemm_mfma(const u16* __restrict__ A, const u16* __restrict__ W,
               const float* __restrict__ bias, void* __restrict__ Cp,
               int M, int N, int K, int ldc) {
  __shared__ __align__(16) u16 SM[24576];   // 48 KiB
  const int tid = threadIdx.x;
  const int wave = tid >> 6, lane = tid & 63;

  const int gx = gridDim.x;
  const int nwg = gx * (int)gridDim.y;
  const int flat = (int)blockIdx.y * gx + (int)blockIdx.x;
  const int xcd = flat & 7, lo = flat >> 3;
  const int q = nwg >> 3, r = nwg & 7;
  const int swz = (xcd < r ? xcd * (q + 1) : r * (q + 1) + (xcd - r) * q) + lo;
  const int bm = (swz / gx) * 128, bn = (swz % gx) * 128;

  const int wm = (wave & 1) * 64, wn = (wave >> 1) * 64;
  const int srow = tid >> 2, selem = (tid & 3) * 8;
  const u16* Ap0 = A + (size_t)(bm + srow) * K + selem;
  const u16* Ap1 = A + (size_t)(bm + srow + 64) * K + selem;
  const u16* Wp0 = W + (size_t)(bn + srow) * K + selem;
  const u16* Wp1 = W + (size_t)(bn + srow + 64) * K + selem;
  const int fr = lane & 15, fq = (lane >> 4) * 8;

  f32x4 acc[4][4];
#pragma unroll
  for (int i = 0; i < 4; ++i)
#pragma unroll
    for (int j = 0; j < 4; ++j) acc[i][j] = (f32x4){0.f, 0.f, 0.f, 0.f};

  const int nt = K >> 5;

  auto stage = [&](int buf, int k0) {
    u16* AsD = SM + buf * 4096 + tid * 8;
    u16* BsD = SM + 12288 + buf * 4096 + tid * 8;
    async_ld16(AsD, Ap0 + k0);
    async_ld16(AsD + 2048, Ap1 + k0);
    async_ld16(BsD, Wp0 + k0);
    async_ld16(BsD + 2048, Wp1 + k0);
  };

  stage(0, 0);
  if (nt > 1) stage(1, 32);

  int bi = 0;
  for (int t = 0; t < nt; ++t) {
    if (t + 1 < nt) asm volatile("s_waitcnt vmcnt(4)" ::: "memory");
    else            asm volatile("s_waitcnt vmcnt(0)" ::: "memory");
    __builtin_amdgcn_s_barrier();
    if (t + 2 < nt) {
      int nb = bi + 2; if (nb >= 3) nb -= 3;
      stage(nb, (t + 2) << 5);
    }
    const u16* Asb = SM + bi * 4096;
    const u16* Bsb = SM + 12288 + bi * 4096;
    bf16x8 af[4], bfv[4];
#pragma unroll
    for (int i = 0; i < 4; ++i)
      af[i] = *(const bf16x8*)&Asb[(wm + i * 16 + fr) * 32 + fq];
#pragma unroll
    for (int j = 0; j < 4; ++j)
      bfv[j] = *(const bf16x8*)&Bsb[(wn + j * 16 + fr) * 32 + fq];
#pragma unroll
    for (int i = 0; i < 4; ++i)
#pragma unroll
      for (int j = 0; j < 4; ++j)
        acc[i][j] = __builtin_amdgcn_mfma_f32_16x16x32_bf16(af[i], bfv[j], acc[i][j], 0, 0, 0);
    if (++bi == 3) bi = 0;
  }

  __syncthreads();
  const int lrow = (lane >> 4) * 4;
  const int colb = wn + fr;

  if (OUTM == 0) {
    u16* Ep = SM;
#pragma unroll
    for (int j = 0; j < 4; ++j) {
      float bv = bias[bn + colb + j * 16];
#pragma unroll
      for (int i = 0; i < 4; ++i)
#pragma unroll
        for (int rr = 0; rr < 4; ++rr) {
          float v = acc[i][j][rr] + bv;
          if (ACT == 1) v = v / (1.f + __expf(-v));
          else if (ACT == 2) v = 0.5f * v * (1.f + erff(v * 0.70710678118f));
          Ep[(wm + i * 16 + lrow + rr) * 128 + colb + j * 16] = f2bf(v);
        }
    }
    __syncthreads();
#pragma unroll
    for (int it = 0; it < 8; ++it) {
      int idx = it * 256 + tid;
      int row = idx >> 4, c = idx & 15;
      *(uint4*)((u16*)Cp + (size_t)(bm + row) * ldc + bn + c * 8) =
          ((const uint4*)Ep)[idx];
    }
  } else {
    float* Ep = (float*)SM;
    float* Cf = (float*)Cp;
#pragma unroll
    for (int ch = 0; ch < 2; ++ch) {
      if ((wave & 1) == ch) {
#pragma unroll
        for (int j = 0; j < 4; ++j) {
          float bv = bias[bn + colb + j * 16];
#pragma unroll
          for (int i = 0; i < 4; ++i)
#pragma unroll
            for (int rr = 0; rr < 4; ++rr) {
              float v = acc[i][j][rr] + bv;
              if (ACT == 1) v = v / (1.f + __expf(-v));
              else if (ACT == 2) v = 0.5f * v * (1.f + erff(v * 0.70710678118f));
              Ep[(i * 16 + lrow + rr) * 128 + colb + j * 16] = v;
            }
        }
      }
      __syncthreads();
#pragma unroll
      for (int it = 0; it < 8; ++it) {
        int idx = it * 256 + tid;
        int row = idx >> 5, c4 = idx & 31;
        size_t g = (size_t)(bm + ch * 64 + row) * ldc + bn + c4 * 4;
        float4 sv = ((const float4*)Ep)[idx];
        if (OUTM == 1) {
          float4 od = *(const float4*)(Cf + g);
          sv.x += od.x; sv.y += od.y; sv.z += od.z; sv.w += od.w;
        }
        *(float4*)(Cf + g) = sv;
      }
      __syncthreads();
    }
  }
}

// =====================================================================
// Big-shape MFMA GEMM: 256x256 tile, 8 waves (2Mx4N), BK=64,
// 2 LDS K-tile buffers (128 KiB), 4-phase schedule per K-tile:
//   P1: vmcnt(8)+bar; dsr A(mi0-3)+B(nj0-1); 16 MFMA; bar
//   P2: dsr B(nj2-3); 16 MFMA; bar
//   P3: dsr A(mi4-7); 16 MFMA; bar      <- all reads of buf[t&1] done
//   P4: stage tile t+2 -> buf[t&1]; 16 reg-only MFMA
// Counted vmcnt(8) steady state (never 0 mid-loop). T2 XOR chunk swizzle
// (16B chunk ^= row&7) applied BOTH at the pre-swizzled global source and
// the ds_read address. setprio(1) around MFMA clusters. Coalesced
// LDS-staged epilogue (R3 lesson). Requires M%256==0,N%256==0,K%64==0,K>=128.
// =====================================================================
template<int ACT, int OUTM>
__global__ __launch_bounds__(512, 2)
void gemm_mfma256(const u16* __restrict__ A, const u16* __restrict__ W,
                  const float* __restrict__ bias, void* __restrict__ Cp,
                  int M, int N, int K, int ldc) {
  __shared__ __align__(16) u16 SM[65536];   // 128 KiB: [2][A 16K u16 | B 16K u16]
  const int tid = threadIdx.x;
  const int wave = tid >> 6, lane = tid & 63;
  const int wave_m = wave >> 2, wave_n = wave & 3;   // 2 x 4
  const int WM = wave_m * 128, WN = wave_n * 64;

  // bijective XCD-chunk swizzle (m204)
  const int gx = gridDim.x;
  const int nwg = gx * (int)gridDim.y;
  const int flat = (int)blockIdx.y * gx + (int)blockIdx.x;
  const int xcd = flat & 7, lo = flat >> 3;
  const int q = nwg >> 3, r = nwg & 7;
  const int swz = (xcd < r ? xcd * (q + 1) : r * (q + 1) + (xcd - r) * q) + lo;
  const int bm = (swz / gx) * 256, bn = (swz % gx) * 256;

  // ---- staging map (pre-swizzled source; linear LDS dest) ----
  // thread covers physical LDS 16B chunk: row q*64+(tid>>3), phys chunk tid&7.
  // stored logical chunk = (tid&7) ^ (row&7); row&7 == (tid>>3)&7.
  const int srow = tid >> 3;                       // 0..63
  const int slc = (tid & 7) ^ (srow & 7);          // logical 16B chunk index
  const u16* Asrc = A + (size_t)(bm + srow) * K + slc * 8;
  const u16* Wsrc = W + (size_t)(bn + srow) * K + slc * 8;

  auto stage = [&](int buf, int k0) {
    u16* Ad = SM + buf * 32768 + tid * 8;
    u16* Bd = SM + buf * 32768 + 16384 + tid * 8;
#pragma unroll
    for (int qq = 0; qq < 4; ++qq)
      async_ld16(Ad + qq * 4096, Asrc + (size_t)qq * 64 * K + k0);
#pragma unroll
    for (int qq = 0; qq < 4; ++qq)
      async_ld16(Bd + qq * 4096, Wsrc + (size_t)qq * 64 * K + k0);
  };

  // ---- fragment read addressing (swizzle-aware) ----
  // logical chunk for (ks, lane) = ks*4 + (lane>>4); phys = logical ^ (row&7);
  // row&7 == fr&7. elem addr = row*64 + phys*8.
  const int fr = lane & 15;
  const int pc0 = (((lane >> 4) ^ (fr & 7))) * 8;  // phys chunk elem-offset, ks=0
  const int arow0 = (WM + fr) * 64;                // + mi*1024
  const int brow0 = (WN + fr) * 64;                // + nj*1024

  f32x4 acc[8][4];
#pragma unroll
  for (int i = 0; i < 8; ++i)
#pragma unroll
    for (int j = 0; j < 4; ++j) acc[i][j] = (f32x4){0.f, 0.f, 0.f, 0.f};

  const int nt = K >> 6;   // BK = 64

  stage(0, 0);
  if (nt > 1) stage(1, 64);

  bf16x8 aA[4][2], bB[4][2];

#pragma unroll 1
  for (int t = 0; t < nt; ++t) {
    const u16* Ab = SM + (t & 1) * 32768;
    const u16* Bb = Ab + 16384;
    // tile t must be landed; tile t+1's 8 loads may stay in flight
    if (t + 1 < nt) asm volatile("s_waitcnt vmcnt(8)" ::: "memory");
    else            asm volatile("s_waitcnt vmcnt(0)" ::: "memory");
    fbar();
    // ---- P1: A rows 0-3, B cols 0-1 ----
#pragma unroll
    for (int mi = 0; mi < 4; ++mi)
#pragma unroll
      for (int ks = 0; ks < 2; ++ks)
        aA[mi][ks] = *(const bf16x8*)&Ab[arow0 + mi * 1024 + (pc0 ^ (ks * 32))];
#pragma unroll
    for (int nj = 0; nj < 2; ++nj)
#pragma unroll
      for (int ks = 0; ks < 2; ++ks)
        bB[nj][ks] = *(const bf16x8*)&Bb[brow0 + nj * 1024 + (pc0 ^ (ks * 32))];
    __builtin_amdgcn_s_setprio(1);
#pragma unroll
    for (int mi = 0; mi < 4; ++mi)
#pragma unroll
      for (int nj = 0; nj < 2; ++nj)
#pragma unroll
        for (int ks = 0; ks < 2; ++ks)
          acc[mi][nj] = __builtin_amdgcn_mfma_f32_16x16x32_bf16(aA[mi][ks], bB[nj][ks], acc[mi][nj], 0, 0, 0);
    __builtin_amdgcn_s_setprio(0);
    fbar();
    // ---- P2: B cols 2-3 ----
#pragma unroll
    for (int nj = 2; nj < 4; ++nj)
#pragma unroll
      for (int ks = 0; ks < 2; ++ks)
        bB[nj][ks] = *(const bf16x8*)&Bb[brow0 + nj * 1024 + (pc0 ^ (ks * 32))];
    __builtin_amdgcn_s_setprio(1);
#pragma unroll
    for (int mi = 0; mi < 4; ++mi)
#pragma unroll
      for (int nj = 2; nj < 4; ++nj)
#pragma unroll
        for (int ks = 0; ks < 2; ++ks)
          acc[mi][nj] = __builtin_amdgcn_mfma_f32_16x16x32_bf16(aA[mi][ks], bB[nj][ks], acc[mi][nj], 0, 0, 0);
    __builtin_amdgcn_s_setprio(0);
    fbar();
    // ---- P3: A rows 4-7 ----
#pragma unroll
    for (int mi = 0; mi < 4; ++mi)
#pragma unroll
      for (int ks = 0; ks < 2; ++ks)
        aA[mi][ks] = *(const bf16x8*)&Ab[arow0 + (mi + 4) * 1024 + (pc0 ^ (ks * 32))];
    __builtin_amdgcn_s_setprio(1);
#pragma unroll
    for (int mi = 0; mi < 4; ++mi)
#pragma unroll
      for (int nj = 2; nj < 4; ++nj)
#pragma unroll
        for (int ks = 0; ks < 2; ++ks)
          acc[mi + 4][nj] = __builtin_amdgcn_mfma_f32_16x16x32_bf16(aA[mi][ks], bB[nj][ks], acc[mi + 4][nj], 0, 0, 0);
    __builtin_amdgcn_s_setprio(0);
    fbar();   // <- after this barrier no wave reads buf[t&1] again
    // ---- P4: stage tile t+2 into buf[t&1]; reg-only MFMA ----
    if (t + 2 < nt) stage(t & 1, (t + 2) << 6);
    __builtin_amdgcn_s_setprio(1);
#pragma unroll
    for (int mi = 0; mi < 4; ++mi)
#pragma unroll
      for (int nj = 0; nj < 2; ++nj)
#pragma unroll
        for (int ks = 0; ks < 2; ++ks)
          acc[mi + 4][nj] = __builtin_amdgcn_mfma_f32_16x16x32_bf16(aA[mi][ks], bB[nj][ks], acc[mi + 4][nj], 0, 0, 0);
    __builtin_amdgcn_s_setprio(0);
  }

  // ---------------- coalesced LDS-staged epilogue ----------------
  fbar();   // all waves done with K-loop LDS before reuse
  const int lrow = (lane >> 4) * 4;
  const int colb = WN + fr;   // + nj*16

  if (OUTM == 0) {
    u16* Ep = SM;   // [256][256] bf16 = 128 KiB exactly
#pragma unroll
    for (int nj = 0; nj < 4; ++nj) {
      float bv = bias[bn + colb + nj * 16];
#pragma unroll
      for (int mi = 0; mi < 8; ++mi)
#pragma unroll
        for (int rr = 0; rr < 4; ++rr) {
          float v = acc[mi][nj][rr] + bv;
          if (ACT == 1) v = v / (1.f + __expf(-v));
          else if (ACT == 2) v = 0.5f * v * (1.f + erff(v * 0.70710678118f));
          Ep[(WM + mi * 16 + lrow + rr) * 256 + colb + nj * 16] = f2bf(v);
        }
    }
    __syncthreads();
    // 256x256 bf16 = 8192 uint4; 16 per thread; 32 uint4 per row
#pragma unroll
    for (int it = 0; it < 16; ++it) {
      int idx = it * 512 + tid;
      int row = idx >> 5, c = idx & 31;
      *(uint4*)((u16*)Cp + (size_t)(bm + row) * ldc + bn + c * 8) =
          ((const uint4*)Ep)[idx];
    }
  } else {
    float* Ep = (float*)SM;   // [128][256] fp32 = 128 KiB, two row-chunks
    float* Cf = (float*)Cp;
#pragma unroll
    for (int ch = 0; ch < 2; ++ch) {
      if (wave_m == ch) {
#pragma unroll
        for (int nj = 0; nj < 4; ++nj) {
          float bv = bias[bn + colb + nj * 16];
#pragma unroll
          for (int mi = 0; mi < 8; ++mi)
#pragma unroll
            for (int rr = 0; rr < 4; ++rr) {
              float v = acc[mi][nj][rr] + bv;
              if (ACT == 1) v = v / (1.f + __expf(-v));
              else if (ACT == 2) v = 0.5f * v * (1.f + erff(v * 0.70710678118f));
              Ep[(mi * 16 + lrow + rr) * 256 + colb + nj * 16] = v;
            }
        }
      }
      __syncthreads();
      // 128x256 fp32 = 8192 float4; 16/thread; 64 float4 per row
#pragma unroll
      for (int it = 0; it < 16; ++it) {
        int idx = it * 512 + tid;
        int row = idx >> 6, c4 = idx & 63;
        size_t g = (size_t)(bm + ch * 128 + row) * ldc + bn + c4 * 4;
        float4 sv = ((const float4*)Ep)[idx];
        if (OUTM == 1) {
          float4 od = *(const float4*)(Cf + g);
          sv.x += od.x; sv.y += od.y; sv.z += od.z; sv.w += od.w;
        }
        *(float4*)(Cf + g) = sv;
      }
      __syncthreads();
    }
  }
}

// ---------- LayerNorm over D=512: fp32 in, fp32 w/b, bf16 out ----------
__global__ __launch_bounds__(256)
void k_layernorm(const float* __restrict__ X, const float* __restrict__ w,
                 const float* __restrict__ b, u16* __restrict__ Y) {
  int row = blockIdx.x, tid = threadIdx.x;
  const float* x = X + (size_t)row * 512;
  float v0 = x[tid], v1 = x[tid + 256];
  __shared__ float red[4];
  float s = v0 + v1;
  for (int o = 32; o; o >>= 1) s += __shfl_down(s, o, 64);
  if ((tid & 63) == 0) red[tid >> 6] = s;
  __syncthreads();
  if (tid == 0) red[0] = (red[0] + red[1] + red[2] + red[3]) * (1.f / 512.f);
  __syncthreads();
  float mean = red[0];
  __syncthreads();
  float d0 = v0 - mean, d1 = v1 - mean;
  float q = d0 * d0 + d1 * d1;
  for (int o = 32; o; o >>= 1) q += __shfl_down(q, o, 64);
  if ((tid & 63) == 0) red[tid >> 6] = q;
  __syncthreads();
  if (tid == 0) red[0] = (red[0] + red[1] + red[2] + red[3]) * (1.f / 512.f);
  __syncthreads();
  float rstd = rsqrtf(red[0] + 1e-5f);
  size_t o0 = (size_t)row * 512 + tid;
  Y[o0] = f2bf(d0 * rstd * w[tid] + b[tid]);
  Y[o0 + 256] = f2bf(d1 * rstd * w[tid + 256] + b[tid + 256]);
}

// ---------- condition input gather (fp32 tables -> bf16, padded to 320) ----------
__global__ void k_cond_gather(const int* __restrict__ note_id, const int* __restrict__ phon_id,
                              const int* __restrict__ slur, const int* __restrict__ pp,
                              const float* __restrict__ note_emb, const float* __restrict__ phon_emb,
                              const float* __restrict__ slur_emb, const float* __restrict__ pp_emb,
                              u16* __restrict__ out) {
  int bt = blockIdx.x, t = threadIdx.x;  // block = 320
  u16 v = 0;
  if (t < 128) v = f2bf(note_emb[note_id[bt] * 128 + t]);
  else if (t < 256) v = f2bf(phon_emb[phon_id[bt] * 128 + (t - 128)]);
  else if (t < 272) {
    int sv = slur[bt]; sv = sv < 0 ? 0 : (sv > 1 ? 1 : sv);
    v = f2bf(slur_emb[sv * 16 + (t - 256)]);
  } else if (t < 304) v = f2bf(pp_emb[pp[bt] * 32 + (t - 272)]);
  out[bt * 320 + t] = v;
}

// pad+cast cond_w1 [256,304] fp32 -> [256,320] bf16
__global__ void k_pad_w(const float* __restrict__ w, u16* __restrict__ out) {
  int n = blockIdx.x, t = threadIdx.x;  // grid 256, block 320
  out[n * 320 + t] = (t < 304) ? f2bf(w[n * 304 + t]) : (u16)0;
}

// gather temb(bf16)[codes[...,0]] -> f_emb [32768,256] (uint4 = 8 bf16)
__global__ void k_femb(const int* __restrict__ codes, const uint4* __restrict__ emb,
                       uint4* __restrict__ out) {
  int i = blockIdx.x * 256 + threadIdx.x;  // < 32768*32
  int m = i >> 5, c = i & 31;
  out[i] = emb[(size_t)codes[m * 2] * 32 + c];
}

// pooled[bt,c] = mean_s f_emb[bt*64+s, c]
__global__ void k_pool(const u16* __restrict__ femb, u16* __restrict__ pooled) {
  int bt = blockIdx.x, c = threadIdx.x;  // block 256
  float s = 0.f;
  for (int j = 0; j < 64; ++j) s += bf2f(femb[((size_t)bt * 64 + j) * 256 + c]);
  pooled[bt * 256 + c] = f2bf(s * (1.f / 64.f));
}

// step_in[bt] = [cond[bt] | (t==0 ? bos(fp32) : prevo[bt-1])]
__global__ void k_stepin(const u16* __restrict__ cond, const u16* __restrict__ prevo,
                         const float* __restrict__ bosf, u16* __restrict__ out) {
  int bt = blockIdx.x, t = threadIdx.x;  // block 512
  u16 v;
  if (t < 256) v = cond[bt * 256 + t];
  else {
    int tt = bt & 127;
    v = (tt == 0) ? f2bf(bosf[t - 256]) : prevo[(bt - 1) * 256 + (t - 256)];
  }
  out[bt * 512 + t] = v;
}

// ---------- ctx attention: one wave per (b,h,t), window 32 causal ----------
__global__ __launch_bounds__(64)
void k_ctx_attn(const u16* __restrict__ qkv, u16* __restrict__ out) {
  int t = blockIdx.x, h = blockIdx.y, b = blockIdx.z;
  int lane = threadIdx.x;
  int bt = b * 128 + t;
  float qd = bf2f(qkv[(size_t)bt * 1536 + h * 64 + lane]) * 0.125f;
  int klo = t - 31; if (klo < 0) klo = 0;
  int n = t - klo + 1;
  __shared__ float sc[32];
  for (int i = 0; i < n; ++i) {
    float p = qd * bf2f(qkv[((size_t)(b * 128 + klo + i)) * 1536 + 512 + h * 64 + lane]);
    for (int o = 32; o; o >>= 1) p += __shfl_xor(p, o, 64);
    if (lane == 0) sc[i] = p;
  }
  __syncthreads();
  float mx = -1e30f;
  for (int i = 0; i < n; ++i) mx = fmaxf(mx, sc[i]);
  float den = 0.f, acc = 0.f;
  for (int i = 0; i < n; ++i) {
    float p = __expf(sc[i] - mx);
    den += p;
    acc += p * bf2f(qkv[((size_t)(b * 128 + klo + i)) * 1536 + 1024 + h * 64 + lane]);
  }
  out[(size_t)bt * 512 + h * 64 + lane] = f2bf(acc / den);
}

// ---------- audio attention, MFMA: one wave per (seq,head); S=64, D=64, causal ----------
__global__ __launch_bounds__(128)
void k_aud_attn_mfma(const u16* __restrict__ qkv, u16* __restrict__ out) {
  constexpr int LP = 66;
  __shared__ u16 Pl[2][64 * LP];
  __shared__ u16 Vt[2][64 * LP];
  const int wave = threadIdx.x >> 6, lane = threadIdx.x & 63;
  const int id = blockIdx.x * 2 + wave;       // 0..4095
  const int seq = id >> 3, h = id & 7;
  const u16* Qb = qkv + (size_t)seq * 64 * 1536 + h * 64;
  const u16* Kb = Qb + 512;
  const u16* Vb = Qb + 1024;
  u16* Plw = Pl[wave];
  u16* Vtw = Vt[wave];
  const int fr = lane & 15, fq = (lane >> 4) * 8;

#pragma unroll
  for (int t = 0; t < 8; ++t) {
    int vr = (lane >> 3) + 8 * t, vc = (lane & 7) * 8;
    uint4 vv = *(const uint4*)(Vb + (size_t)vr * 1536 + vc);
    Vtw[(vc + 0) * LP + vr] = (u16)(vv.x & 0xffff);
    Vtw[(vc + 1) * LP + vr] = (u16)(vv.x >> 16);
    Vtw[(vc + 2) * LP + vr] = (u16)(vv.y & 0xffff);
    Vtw[(vc + 3) * LP + vr] = (u16)(vv.y >> 16);
    Vtw[(vc + 4) * LP + vr] = (u16)(vv.z & 0xffff);
    Vtw[(vc + 5) * LP + vr] = (u16)(vv.z >> 16);
    Vtw[(vc + 6) * LP + vr] = (u16)(vv.w & 0xffff);
    Vtw[(vc + 7) * LP + vr] = (u16)(vv.w >> 16);
  }

  bf16x8 aq[4][2], bk[4][2];
#pragma unroll
  for (int i = 0; i < 4; ++i)
#pragma unroll
    for (int c = 0; c < 2; ++c) {
      aq[i][c] = *(const bf16x8*)(Qb + (size_t)(i * 16 + fr) * 1536 + fq + 32 * c);
      bk[i][c] = *(const bf16x8*)(Kb + (size_t)(i * 16 + fr) * 1536 + fq + 32 * c);
    }
  f32x4 s[4][4];
#pragma unroll
  for (int i = 0; i < 4; ++i)
#pragma unroll
    for (int j = 0; j < 4; ++j) s[i][j] = (f32x4){0.f, 0.f, 0.f, 0.f};
#pragma unroll
  for (int c = 0; c < 2; ++c)
#pragma unroll
    for (int i = 0; i < 4; ++i)
#pragma unroll
      for (int j = 0; j < 4; ++j)
        s[i][j] = __builtin_amdgcn_mfma_f32_16x16x32_bf16(aq[i][c], bk[j][c], s[i][j], 0, 0, 0);

  const int qr = (lane >> 4) * 4;
#pragma unroll
  for (int i = 0; i < 4; ++i) {
#pragma unroll
    for (int r = 0; r < 4; ++r) {
      int row = 16 * i + qr + r;
      float mx = -1e30f;
      float vj[4];
#pragma unroll
      for (int j = 0; j < 4; ++j) {
        float v = s[i][j][r] * 0.125f;
        if (16 * j + fr > row) v = -1e30f;   // causal
        vj[j] = v;
        mx = fmaxf(mx, v);
      }
      for (int o = 8; o; o >>= 1) mx = fmaxf(mx, __shfl_xor(mx, o, 64));
      float den = 0.f;
#pragma unroll
      for (int j = 0; j < 4; ++j) { vj[j] = __expf(vj[j] - mx); den += vj[j]; }
      for (int o = 8; o; o >>= 1) den += __shfl_xor(den, o, 64);
      float inv = 1.f / den;
#pragma unroll
      for (int j = 0; j < 4; ++j)
        Plw[row * LP + 16 * j + fr] = f2bf(vj[j] * inv);
    }
  }
  __syncthreads();

  f32x4 o4[4][4];
#pragma unroll
  for (int i = 0; i < 4; ++i)
#pragma unroll
    for (int j = 0; j < 4; ++j) o4[i][j] = (f32x4){0.f, 0.f, 0.f, 0.f};
#pragma unroll
  for (int c = 0; c < 2; ++c) {
    bf16x8 ap[4], bv[4];
#pragma unroll
    for (int i = 0; i < 4; ++i)
      ap[i] = *(const bf16x8*)&Plw[(16 * i + fr) * LP + fq + 32 * c];
#pragma unroll
    for (int j = 0; j < 4; ++j)
      bv[j] = *(const bf16x8*)&Vtw[(16 * j + fr) * LP + fq + 32 * c];
#pragma unroll
    for (int i = 0; i < 4; ++i)
#pragma unroll
      for (int j = 0; j < 4; ++j)
        o4[i][j] = __builtin_amdgcn_mfma_f32_16x16x32_bf16(ap[i], bv[j], o4[i][j], 0, 0, 0);
  }
#pragma unroll
  for (int i = 0; i < 4; ++i)
#pragma unroll
    for (int r = 0; r < 4; ++r) {
      int row = 16 * i + qr + r;
      u16* ob = out + ((size_t)seq * 64 + row) * 512 + h * 64;
#pragma unroll
      for (int j = 0; j < 4; ++j) ob[16 * j + fr] = f2bf(o4[i][j][r]);
    }
}

// a[row,d] = (s==0 ? bos(fp32) : tok[row-1](bf16)) + frame_pos[s](fp32) + h[bt](fp32)
__global__ void k_abuild(const uint4* __restrict__ tok, const float4* __restrict__ bosf,
                         const float4* __restrict__ fpos, const float4* __restrict__ hstep,
                         float4* __restrict__ a) {
  size_t i = (size_t)blockIdx.x * 256 + threadIdx.x;  // < 32768*64
  int d8 = (int)(i & 63);
  size_t row = i >> 6;
  int s = (int)(row & 63);
  size_t bt = row >> 6;
  float t0, t1, t2, t3, t4, t5, t6, t7;
  if (s == 0) {
    float4 b0 = bosf[d8 * 2], b1 = bosf[d8 * 2 + 1];
    t0 = b0.x; t1 = b0.y; t2 = b0.z; t3 = b0.w;
    t4 = b1.x; t5 = b1.y; t6 = b1.z; t7 = b1.w;
  } else {
    uint4 tv = tok[(row - 1) * 64 + d8];
    t0 = lo16(tv.x); t1 = hi16(tv.x); t2 = lo16(tv.y); t3 = hi16(tv.y);
    t4 = lo16(tv.z); t5 = hi16(tv.z); t6 = lo16(tv.w); t7 = hi16(tv.w);
  }
  float4 f0 = fpos[(size_t)s * 128 + d8 * 2], f1 = fpos[(size_t)s * 128 + d8 * 2 + 1];
  float4 h0 = hstep[bt * 128 + d8 * 2], h1 = hstep[bt * 128 + d8 * 2 + 1];
  float4 o0, o1;
  o0.x = t0 + f0.x + h0.x; o0.y = t1 + f0.y + h0.y;
  o0.z = t2 + f0.z + h0.z; o0.w = t3 + f0.w + h0.w;
  o1.x = t4 + f1.x + h1.x; o1.y = t5 + f1.y + h1.y;
  o1.z = t6 + f1.z + h1.z; o1.w = t7 + f1.w + h1.w;
  a[i * 2] = o0; a[i * 2 + 1] = o1;
}

// cat[m] = [ah[m] | tok[m]]  (uint4 = 8 bf16)
__global__ void k_cat(const uint4* __restrict__ ah, const uint4* __restrict__ tok,
                      uint4* __restrict__ out) {
  size_t i = (size_t)blockIdx.x * 256 + threadIdx.x;  // < 32768*128
  size_t m = i >> 7;
  int c = (int)(i & 127);
  out[i] = (c < 64) ? ah[m * 64 + c] : tok[m * 64 + (c - 64)];
}

// ---------- host side ----------
template<int ACT, int OUTM>
static inline void gemm(const u16* A, const u16* W, const float* bias, void* C,
                        int M, int N, int K, int ldc, hipStream_t s) {
  gemm_mfma<ACT, OUTM><<<dim3(N / 128, M / 128), 256, 0, s>>>(A, W, bias, C, M, N, K, ldc);
}

template<int ACT, int OUTM>
static inline void gemmBig(const u16* A, const u16* W, const float* bias, void* C,
                           int M, int N, int K, int ldc, hipStream_t s) {
  gemm_mfma256<ACT, OUTM><<<dim3(N / 256, M / 256), 512, 0, s>>>(A, W, bias, C, M, N, K, ldc);
}

static inline void cast_bf16(const float* x, u16* y, size_t n, hipStream_t s) {
  int n8 = (int)(n / 8);
  k_cast8<<<(n8 + 255) / 256, 256, 0, s>>>((const float4*)x, (uint4*)y, n8);
}

extern "C" void kernel_launch(void* const* d_in, const int* in_sizes, int n_in,
                              void* d_out, int out_size, void* d_ws, size_t ws_size,
                              hipStream_t stream) {
  const int* codes    = (const int*)d_in[0];
  const int* note_id  = (const int*)d_in[1];
  const int* phon_id  = (const int*)d_in[2];
  const int* slur     = (const int*)d_in[3];
  const int* pprog    = (const int*)d_in[4];
  const float* note_emb = (const float*)d_in[5];
  const float* phon_emb = (const float*)d_in[6];
  const float* slur_emb = (const float*)d_in[7];
  const float* pp_emb   = (const float*)d_in[8];
  const float* cond_w1  = (const float*)d_in[9];
  const float* cond_b1  = (const float*)d_in[10];
  const float* cond_w2  = (const float*)d_in[11];
  const float* cond_b2  = (const float*)d_in[12];
  const float* tok_emb  = (const float*)d_in[13];
  const float* prev_w1  = (const float*)d_in[14];
  const float* prev_b1  = (const float*)d_in[15];
  const float* prev_w2  = (const float*)d_in[16];
  const float* prev_b2  = (const float*)d_in[17];
  const float* bos_step = (const float*)d_in[18];
  const float* step_w1  = (const float*)d_in[19];
  const float* step_b1  = (const float*)d_in[20];
  const float* step_w2  = (const float*)d_in[21];
  const float* step_b2  = (const float*)d_in[22];
  const float* audio_in_w = (const float*)d_in[23];
  const float* audio_in_b = (const float*)d_in[24];
  const float* audio_bos  = (const float*)d_in[25];
  const float* frame_pos  = (const float*)d_in[26];
  const float* first_w  = (const float*)d_in[27];
  const float* first_b  = (const float*)d_in[28];
  const float* resc_w1  = (const float*)d_in[29];
  const float* resc_b1  = (const float*)d_in[30];
  const float* resc_w2  = (const float*)d_in[31];
  const float* resc_b2  = (const float*)d_in[32];
  const float* res_w    = (const float*)d_in[33];
  const float* res_b    = (const float*)d_in[34];
  const float* ctx_w[12]; for (int i = 0; i < 12; ++i) ctx_w[i] = (const float*)d_in[35 + i];
  const float* aud_w[12]; for (int i = 0; i < 12; ++i) aud_w[i] = (const float*)d_in[47 + i];

  // workspace layout (deterministic every call)
  char* p = (char*)d_ws;
  auto alloc = [&](size_t b) { char* r = p; p += (b + 255) & ~(size_t)255; return r; };
  float* A_res = (float*)alloc(32768ull * 512 * 4);   // audio residual stream (fp32)
  u16* T_tok  = (u16*)alloc(32768ull * 512 * 2);      // tok (later reused for rh)
  u16* LNb    = (u16*)alloc(32768ull * 512 * 2);      // ln out / ah bf16
  u16* AOb    = (u16*)alloc(32768ull * 512 * 2);      // attn out / resc mid
  u16* QF     = (u16*)alloc(32768ull * 2048 * 2);     // qkv / ffn-mid / cat
  u16* f_emb  = (u16*)alloc(32768ull * 256 * 2);
  u16* temb   = (u16*)alloc(1024ull * 256 * 2);       // token_emb bf16
  u16* cond_in = (u16*)alloc(512ull * 320 * 2);
  u16* cw1p   = (u16*)alloc(256ull * 320 * 2);
  u16* cw2    = (u16*)alloc(256ull * 256 * 2);
  u16* pw1    = (u16*)alloc(256ull * 256 * 2);
  u16* pw2    = (u16*)alloc(256ull * 256 * 2);
  u16* sw1    = (u16*)alloc(512ull * 512 * 2);
  u16* sw2    = (u16*)alloc(512ull * 512 * 2);
  u16* ainw   = (u16*)alloc(512ull * 256 * 2);
  u16* fw     = (u16*)alloc(1024ull * 512 * 2);
  u16* rw1    = (u16*)alloc(512ull * 1024 * 2);
  u16* rw2    = (u16*)alloc(512ull * 512 * 2);
  u16* resw   = (u16*)alloc(1024ull * 512 * 2);
  u16* cxin   = (u16*)alloc(4ull * 1536 * 512 * 2);
  u16* cxout  = (u16*)alloc(4ull * 512 * 512 * 2);
  u16* cxf1   = (u16*)alloc(4ull * 2048 * 512 * 2);
  u16* cxf2   = (u16*)alloc(4ull * 512 * 2048 * 2);
  u16* adin   = (u16*)alloc(6ull * 1536 * 512 * 2);
  u16* adout  = (u16*)alloc(6ull * 512 * 512 * 2);
  u16* adf1   = (u16*)alloc(6ull * 2048 * 512 * 2);
  u16* adf2   = (u16*)alloc(6ull * 512 * 2048 * 2);
  u16* cond_h = (u16*)alloc(512ull * 256 * 2);
  u16* condv  = (u16*)alloc(512ull * 256 * 2);
  u16* pooled = (u16*)alloc(512ull * 256 * 2);
  u16* prevh  = (u16*)alloc(512ull * 256 * 2);
  u16* prevo  = (u16*)alloc(512ull * 256 * 2);
  u16* stepin = (u16*)alloc(512ull * 512 * 2);
  u16* hmid   = (u16*)alloc(512ull * 512 * 2);
  float* hstep = (float*)alloc(512ull * 512 * 4);     // ctx residual stream (fp32)

  // ---- weight fp32 -> bf16 conversions ----
  k_pad_w<<<256, 320, 0, stream>>>(cond_w1, cw1p);
  cast_bf16(cond_w2, cw2, 256ull * 256, stream);
  cast_bf16(prev_w1, pw1, 256ull * 256, stream);
  cast_bf16(prev_w2, pw2, 256ull * 256, stream);
  cast_bf16(step_w1, sw1, 512ull * 512, stream);
  cast_bf16(step_w2, sw2, 512ull * 512, stream);
  cast_bf16(tok_emb, temb, 1024ull * 256, stream);
  cast_bf16(audio_in_w, ainw, 512ull * 256, stream);
  cast_bf16(first_w, fw, 1024ull * 512, stream);
  cast_bf16(resc_w1, rw1, 512ull * 1024, stream);
  cast_bf16(resc_w2, rw2, 512ull * 512, stream);
  cast_bf16(res_w, resw, 1024ull * 512, stream);
  cast_bf16(ctx_w[2], cxin, 4ull * 1536 * 512, stream);
  cast_bf16(ctx_w[4], cxout, 4ull * 512 * 512, stream);
  cast_bf16(ctx_w[8], cxf1, 4ull * 2048 * 512, stream);
  cast_bf16(ctx_w[10], cxf2, 4ull * 512 * 2048, stream);
  cast_bf16(aud_w[2], adin, 6ull * 1536 * 512, stream);
  cast_bf16(aud_w[4], adout, 6ull * 512 * 512, stream);
  cast_bf16(aud_w[8], adf1, 6ull * 2048 * 512, stream);
  cast_bf16(aud_w[10], adf2, 6ull * 512 * 2048, stream);

  // ---- cond / prev / step ----
  k_cond_gather<<<512, 320, 0, stream>>>(note_id, phon_id, slur, pprog,
                                         note_emb, phon_emb, slur_emb, pp_emb, cond_in);
  k_femb<<<4096, 256, 0, stream>>>(codes, (const uint4*)temb, (uint4*)f_emb);
  k_pool<<<512, 256, 0, stream>>>(f_emb, pooled);
  gemm<1, 0>(cond_in, cw1p, cond_b1, cond_h, 512, 256, 320, 256, stream);
  gemm<0, 0>(cond_h, cw2, cond_b2, condv, 512, 256, 256, 256, stream);
  gemm<1, 0>(pooled, pw1, prev_b1, prevh, 512, 256, 256, 256, stream);
  gemm<0, 0>(prevh, pw2, prev_b2, prevo, 512, 256, 256, 256, stream);
  k_stepin<<<512, 512, 0, stream>>>(condv, prevo, bos_step, stepin);
  gemm<1, 0>(stepin, sw1, step_b1, hmid, 512, 512, 512, 512, stream);
  gemm<0, 2>(hmid, sw2, step_b2, hstep, 512, 512, 512, 512, stream);

  // ---- context transformer (T=128, win=32) ----
  for (int l = 0; l < 4; ++l) {
    k_layernorm<<<512, 256, 0, stream>>>(hstep, ctx_w[0] + l * 512, ctx_w[1] + l * 512, LNb);
    gemm<0, 0>(LNb, cxin + (size_t)l * 1536 * 512, ctx_w[3] + l * 1536, QF, 512, 1536, 512, 1536, stream);
    k_ctx_attn<<<dim3(128, 8, 4), 64, 0, stream>>>(QF, AOb);
    gemm<0, 1>(AOb, cxout + (size_t)l * 512 * 512, ctx_w[5] + l * 512, hstep, 512, 512, 512, 512, stream);
    k_layernorm<<<512, 256, 0, stream>>>(hstep, ctx_w[6] + l * 512, ctx_w[7] + l * 512, LNb);
    gemm<2, 0>(LNb, cxf1 + (size_t)l * 2048 * 512, ctx_w[9] + l * 2048, QF, 512, 2048, 512, 2048, stream);
    gemm<0, 1>(QF, cxf2 + (size_t)l * 512 * 2048, ctx_w[11] + l * 512, hstep, 512, 512, 2048, 512, stream);
  }

  // ---- audio decoder ----
  gemmBig<0, 0>(f_emb, ainw, audio_in_b, T_tok, 32768, 512, 256, 512, stream);
  k_abuild<<<8192, 256, 0, stream>>>((const uint4*)T_tok, (const float4*)audio_bos,
                                     (const float4*)frame_pos, (const float4*)hstep, (float4*)A_res);
  for (int l = 0; l < 6; ++l) {
    k_layernorm<<<32768, 256, 0, stream>>>(A_res, aud_w[0] + l * 512, aud_w[1] + l * 512, LNb);
    gemmBig<0, 0>(LNb, adin + (size_t)l * 1536 * 512, aud_w[3] + l * 1536, QF, 32768, 1536, 512, 1536, stream);
    k_aud_attn_mfma<<<2048, 128, 0, stream>>>(QF, AOb);
    gemmBig<0, 1>(AOb, adout + (size_t)l * 512 * 512, aud_w[5] + l * 512, A_res, 32768, 512, 512, 512, stream);
    k_layernorm<<<32768, 256, 0, stream>>>(A_res, aud_w[6] + l * 512, aud_w[7] + l * 512, LNb);
    gemmBig<2, 0>(LNb, adf1 + (size_t)l * 2048 * 512, aud_w[9] + l * 2048, QF, 32768, 2048, 512, 2048, stream);
    gemmBig<0, 1>(QF, adf2 + (size_t)l * 512 * 2048, aud_w[11] + l * 512, A_res, 32768, 512, 2048, 512, stream);
  }

  // ---- heads (fp32 output) ----
  {
    int n8 = 32768 * 512 / 8;
    k_cast8<<<(n8 + 255) / 256, 256, 0, stream>>>((const float4*)A_res, (uint4*)LNb, n8);
  }
  gemmBig<0, 2>(LNb, fw, first_b, (float*)d_out, 32768, 1024, 512, 2048, stream);          // k=0 slot
  k_cat<<<16384, 256, 0, stream>>>((const uint4*)LNb, (const uint4*)T_tok, (uint4*)QF);
  gemmBig<1, 0>(QF, rw1, resc_b1, AOb, 32768, 512, 1024, 512, stream);
  gemmBig<0, 0>(AOb, rw2, resc_b2, T_tok, 32768, 512, 512, 512, stream);                   // rh
  gemmBig<0, 2>(T_tok, resw, res_b, (float*)d_out + 1024, 32768, 1024, 512, 2048, stream); // k=1 slot
}

// Round 5
// 3475.455 us; speedup vs baseline: 1.3844x; 1.0360x over previous
//
#include <hip/hip_runtime.h>
#include <cstdint>
#include <cstddef>

typedef unsigned short u16;
typedef short bf16x8 __attribute__((ext_vector_type(8)));
typedef float f32x4 __attribute__((ext_vector_type(4)));

// ---------- bf16 helpers ----------
__device__ __forceinline__ float bf2f(u16 u) { return __uint_as_float(((unsigned)u) << 16); }
__device__ __forceinline__ u16 f2bf(float f) {
  unsigned i = __float_as_uint(f);
  i += 0x7fffu + ((i >> 16) & 1u);   // RNE
  return (u16)(i >> 16);
}
__device__ __forceinline__ unsigned packbf2(float lo, float hi) {
  return (unsigned)f2bf(lo) | ((unsigned)f2bf(hi) << 16);
}
__device__ __forceinline__ float lo16(unsigned u) { return __uint_as_float(u << 16); }
__device__ __forceinline__ float hi16(unsigned u) { return __uint_as_float(u & 0xffff0000u); }

// async global->LDS, 16 B per lane; LDS dest = wave-uniform base + lane*16
__device__ __forceinline__ void async_ld16(u16* lds, const u16* g) {
  __builtin_amdgcn_global_load_lds((const __attribute__((address_space(1))) void*)g,
                                   (__attribute__((address_space(3))) void*)lds, 16, 0, 0);
}

// fenced barrier: sched_barrier stops the compiler moving LDS ops across it
__device__ __forceinline__ void fbar() {
  __builtin_amdgcn_sched_barrier(0);
  __builtin_amdgcn_s_barrier();
  __builtin_amdgcn_sched_barrier(0);
}

// ---------- fp32 -> bf16 cast, 8 elems/thread ----------
__global__ void k_cast8(const float4* __restrict__ x, uint4* __restrict__ y, int n8) {
  int i = blockIdx.x * 256 + threadIdx.x;
  if (i >= n8) return;
  float4 a = x[(size_t)i * 2], b = x[(size_t)i * 2 + 1];
  uint4 o;
  o.x = packbf2(a.x, a.y); o.y = packbf2(a.z, a.w);
  o.z = packbf2(b.x, b.y); o.w = packbf2(b.z, b.w);
  y[i] = o;
}

// =====================================================================
// Tiny-shape MFMA GEMM: 64x64 tile, 4 waves (wave w owns 16 output cols),
// BK=32, 3-buffer counted-vmcnt pipeline, 24 KiB LDS (~6 blocks/CU).
// For M=512 shapes the limiter is block-parallelism (8-48 blocks at 128²
// tiles on 256 CUs); 64² quadruples the grid. Direct scalar epilogue is
// fine at these sizes (<=1.5 MB outputs).
// OUTM: 0 bf16 store; 1 fp32 +=; 2 fp32 store.  ACT: 0 none,1 silu,2 gelu.
// =====================================================================
template<int ACT, int OUTM>
__global__ __launch_bounds__(256)
void gemm_mfma64(const u16* __restrict__ A, const u16* __restrict__ W,
                 const float* __restrict__ bias, void* __restrict__ Cp,
                 int M, int N, int K, int ldc) {
  __shared__ __align__(16) u16 SM[12288];   // 24 KiB: 3x(A 2048 + B 2048 u16)
  const int tid = threadIdx.x;
  const int wave = tid >> 6, lane = tid & 63;
  const int bm = blockIdx.y * 64, bn = blockIdx.x * 64;
  const int srow = tid >> 2, selem = (tid & 3) * 8;   // 64 rows x 4 threads
  const u16* Ap = A + (size_t)(bm + srow) * K + selem;
  const u16* Wp = W + (size_t)(bn + srow) * K + selem;
  const int fr = lane & 15, fq = (lane >> 4) * 8;
  const int wn = wave * 16;

  f32x4 acc[4];
#pragma unroll
  for (int i = 0; i < 4; ++i) acc[i] = (f32x4){0.f, 0.f, 0.f, 0.f};

  const int nt = K >> 5;

  auto stage = [&](int buf, int k0) {
    async_ld16(SM + buf * 2048 + tid * 8, Ap + k0);
    async_ld16(SM + 6144 + buf * 2048 + tid * 8, Wp + k0);
  };

  stage(0, 0);
  if (nt > 1) stage(1, 32);

  int bi = 0;
  for (int t = 0; t < nt; ++t) {
    if (t + 1 < nt) asm volatile("s_waitcnt vmcnt(2)" ::: "memory");
    else            asm volatile("s_waitcnt vmcnt(0)" ::: "memory");
    __builtin_amdgcn_s_barrier();
    if (t + 2 < nt) {
      int nb = bi + 2; if (nb >= 3) nb -= 3;
      stage(nb, (t + 2) << 5);
    }
    const u16* Asb = SM + bi * 2048;
    const u16* Bsb = SM + 6144 + bi * 2048;
    bf16x8 af[4];
#pragma unroll
    for (int i = 0; i < 4; ++i)
      af[i] = *(const bf16x8*)&Asb[(i * 16 + fr) * 32 + fq];
    bf16x8 bf1 = *(const bf16x8*)&Bsb[(wn + fr) * 32 + fq];
#pragma unroll
    for (int i = 0; i < 4; ++i)
      acc[i] = __builtin_amdgcn_mfma_f32_16x16x32_bf16(af[i], bf1, acc[i], 0, 0, 0);
    if (++bi == 3) bi = 0;
  }

  // C/D: row = bm + i*16 + (lane>>4)*4 + rr, col = bn + wn + fr
  const int mr = bm + (lane >> 4) * 4;
  const int nc = bn + wn + fr;
  float bv = bias[nc];
#pragma unroll
  for (int i = 0; i < 4; ++i)
#pragma unroll
    for (int rr = 0; rr < 4; ++rr) {
      float v = acc[i][rr] + bv;
      if (ACT == 1) v = v / (1.f + __expf(-v));
      else if (ACT == 2) v = 0.5f * v * (1.f + erff(v * 0.70710678118f));
      size_t off = (size_t)(mr + i * 16 + rr) * ldc + nc;
      if (OUTM == 0) ((u16*)Cp)[off] = f2bf(v);
      else if (OUTM == 1) ((float*)Cp)[off] += v;
      else ((float*)Cp)[off] = v;
    }
}

// =====================================================================
// Big-shape MFMA GEMM: 256x256 tile, 8 waves (2Mx4N), BK=64,
// 2 LDS K-tile buffers (128 KiB), 4-phase schedule per K-tile (proven-
// equal R4 structure), counted vmcnt(8), T2 XOR chunk swizzle on both
// sides, setprio around MFMA clusters, coalesced LDS-staged epilogue.
// SPLITA: A is the virtual concat [A | A2], both halves 512-wide row-major
// (folds the old k_cat pass into staging; branchless per-lane ptr select —
// exec-masking would break global_load_lds's lane-slot contract).
// Requires M%256==0, N%256==0, K%64==0, K>=128.
// =====================================================================
template<int ACT, int OUTM, int SPLITA>
__global__ __launch_bounds__(512, 2)
void gemm_mfma256(const u16* __restrict__ A, const u16* __restrict__ A2,
                  const u16* __restrict__ W,
                  const float* __restrict__ bias, void* __restrict__ Cp,
                  int M, int N, int K, int ldc) {
  __shared__ __align__(16) u16 SM[65536];   // 128 KiB: [2][A 16K u16 | B 16K u16]
  const int tid = threadIdx.x;
  const int wave = tid >> 6, lane = tid & 63;
  const int wave_m = wave >> 2, wave_n = wave & 3;   // 2 x 4
  const int WM = wave_m * 128, WN = wave_n * 64;

  // bijective XCD-chunk swizzle (m204)
  const int gx = gridDim.x;
  const int nwg = gx * (int)gridDim.y;
  const int flat = (int)blockIdx.y * gx + (int)blockIdx.x;
  const int xcd = flat & 7, lo = flat >> 3;
  const int q = nwg >> 3, r = nwg & 7;
  const int swz = (xcd < r ? xcd * (q + 1) : r * (q + 1) + (xcd - r) * q) + lo;
  const int bm = (swz / gx) * 256, bn = (swz % gx) * 256;

  // ---- staging map (pre-swizzled source; linear LDS dest) ----
  const int srow = tid >> 3;                        // 0..63
  const int slc8 = ((tid & 7) ^ (srow & 7)) * 8;    // logical k-offset (elems)
  const u16* Asrc = nullptr; const u16* A2src = nullptr;
  if (SPLITA) {
    Asrc  = A  + (size_t)(bm + srow) * 512;
    A2src = A2 + (size_t)(bm + srow) * 512 - 512;
  } else {
    Asrc = A + (size_t)(bm + srow) * K + slc8;
  }
  const u16* Wsrc = W + (size_t)(bn + srow) * K + slc8;

  auto stage = [&](int buf, int k0) {
    u16* Ad = SM + buf * 32768 + tid * 8;
    u16* Bd = Ad + 16384;
    if (SPLITA) {
      int col = k0 + slc8;                          // 8-chunk never straddles 512
      const u16* s = (col < 512 ? Asrc : A2src) + col;
#pragma unroll
      for (int qq = 0; qq < 4; ++qq)
        async_ld16(Ad + qq * 4096, s + (size_t)qq * 64 * 512);
    } else {
#pragma unroll
      for (int qq = 0; qq < 4; ++qq)
        async_ld16(Ad + qq * 4096, Asrc + (size_t)qq * 64 * K + k0);
    }
#pragma unroll
    for (int qq = 0; qq < 4; ++qq)
      async_ld16(Bd + qq * 4096, Wsrc + (size_t)qq * 64 * K + k0);
  };

  // ---- fragment read addressing (swizzle-aware) ----
  const int fr = lane & 15;
  const int pc0 = (((lane >> 4) ^ (fr & 7))) * 8;  // phys chunk elem-offset, ks=0
  const int arow0 = (WM + fr) * 64;                // + mi*1024
  const int brow0 = (WN + fr) * 64;                // + nj*1024

  f32x4 acc[8][4];
#pragma unroll
  for (int i = 0; i < 8; ++i)
#pragma unroll
    for (int j = 0; j < 4; ++j) acc[i][j] = (f32x4){0.f, 0.f, 0.f, 0.f};

  const int nt = K >> 6;   // BK = 64

  stage(0, 0);
  if (nt > 1) stage(1, 64);

  bf16x8 aA[4][2], bB[4][2];

#pragma unroll 1
  for (int t = 0; t < nt; ++t) {
    const u16* Ab = SM + (t & 1) * 32768;
    const u16* Bb = Ab + 16384;
    if (t + 1 < nt) asm volatile("s_waitcnt vmcnt(8)" ::: "memory");
    else            asm volatile("s_waitcnt vmcnt(0)" ::: "memory");
    fbar();
    // ---- P1: A rows 0-3, B cols 0-1 ----
#pragma unroll
    for (int mi = 0; mi < 4; ++mi)
#pragma unroll
      for (int ks = 0; ks < 2; ++ks)
        aA[mi][ks] = *(const bf16x8*)&Ab[arow0 + mi * 1024 + (pc0 ^ (ks * 32))];
#pragma unroll
    for (int nj = 0; nj < 2; ++nj)
#pragma unroll
      for (int ks = 0; ks < 2; ++ks)
        bB[nj][ks] = *(const bf16x8*)&Bb[brow0 + nj * 1024 + (pc0 ^ (ks * 32))];
    __builtin_amdgcn_s_setprio(1);
#pragma unroll
    for (int mi = 0; mi < 4; ++mi)
#pragma unroll
      for (int nj = 0; nj < 2; ++nj)
#pragma unroll
        for (int ks = 0; ks < 2; ++ks)
          acc[mi][nj] = __builtin_amdgcn_mfma_f32_16x16x32_bf16(aA[mi][ks], bB[nj][ks], acc[mi][nj], 0, 0, 0);
    __builtin_amdgcn_s_setprio(0);
    fbar();
    // ---- P2: B cols 2-3 ----
#pragma unroll
    for (int nj = 2; nj < 4; ++nj)
#pragma unroll
      for (int ks = 0; ks < 2; ++ks)
        bB[nj][ks] = *(const bf16x8*)&Bb[brow0 + nj * 1024 + (pc0 ^ (ks * 32))];
    __builtin_amdgcn_s_setprio(1);
#pragma unroll
    for (int mi = 0; mi < 4; ++mi)
#pragma unroll
      for (int nj = 2; nj < 4; ++nj)
#pragma unroll
        for (int ks = 0; ks < 2; ++ks)
          acc[mi][nj] = __builtin_amdgcn_mfma_f32_16x16x32_bf16(aA[mi][ks], bB[nj][ks], acc[mi][nj], 0, 0, 0);
    __builtin_amdgcn_s_setprio(0);
    fbar();
    // ---- P3: A rows 4-7 ----
#pragma unroll
    for (int mi = 0; mi < 4; ++mi)
#pragma unroll
      for (int ks = 0; ks < 2; ++ks)
        aA[mi][ks] = *(const bf16x8*)&Ab[arow0 + (mi + 4) * 1024 + (pc0 ^ (ks * 32))];
    __builtin_amdgcn_s_setprio(1);
#pragma unroll
    for (int mi = 0; mi < 4; ++mi)
#pragma unroll
      for (int nj = 2; nj < 4; ++nj)
#pragma unroll
        for (int ks = 0; ks < 2; ++ks)
          acc[mi + 4][nj] = __builtin_amdgcn_mfma_f32_16x16x32_bf16(aA[mi][ks], bB[nj][ks], acc[mi + 4][nj], 0, 0, 0);
    __builtin_amdgcn_s_setprio(0);
    fbar();   // <- after this barrier no wave reads buf[t&1] again
    // ---- P4: stage tile t+2 into buf[t&1]; reg-only MFMA ----
    if (t + 2 < nt) stage(t & 1, (t + 2) << 6);
    __builtin_amdgcn_s_setprio(1);
#pragma unroll
    for (int mi = 0; mi < 4; ++mi)
#pragma unroll
      for (int nj = 0; nj < 2; ++nj)
#pragma unroll
        for (int ks = 0; ks < 2; ++ks)
          acc[mi + 4][nj] = __builtin_amdgcn_mfma_f32_16x16x32_bf16(aA[mi][ks], bB[nj][ks], acc[mi + 4][nj], 0, 0, 0);
    __builtin_amdgcn_s_setprio(0);
  }

  // ---------------- coalesced LDS-staged epilogue ----------------
  fbar();   // all waves done with K-loop LDS before reuse
  const int lrow = (lane >> 4) * 4;
  const int colb = WN + fr;   // + nj*16

  if (OUTM == 0) {
    u16* Ep = SM;   // [256][256] bf16 = 128 KiB exactly
#pragma unroll
    for (int nj = 0; nj < 4; ++nj) {
      float bv = bias[bn + colb + nj * 16];
#pragma unroll
      for (int mi = 0; mi < 8; ++mi)
#pragma unroll
        for (int rr = 0; rr < 4; ++rr) {
          float v = acc[mi][nj][rr] + bv;
          if (ACT == 1) v = v / (1.f + __expf(-v));
          else if (ACT == 2) v = 0.5f * v * (1.f + erff(v * 0.70710678118f));
          Ep[(WM + mi * 16 + lrow + rr) * 256 + colb + nj * 16] = f2bf(v);
        }
    }
    __syncthreads();
#pragma unroll
    for (int it = 0; it < 16; ++it) {
      int idx = it * 512 + tid;
      int row = idx >> 5, c = idx & 31;
      *(uint4*)((u16*)Cp + (size_t)(bm + row) * ldc + bn + c * 8) =
          ((const uint4*)Ep)[idx];
    }
  } else {
    float* Ep = (float*)SM;   // [128][256] fp32 = 128 KiB, two row-chunks
    float* Cf = (float*)Cp;
#pragma unroll
    for (int ch = 0; ch < 2; ++ch) {
      if (wave_m == ch) {
#pragma unroll
        for (int nj = 0; nj < 4; ++nj) {
          float bv = bias[bn + colb + nj * 16];
#pragma unroll
          for (int mi = 0; mi < 8; ++mi)
#pragma unroll
            for (int rr = 0; rr < 4; ++rr) {
              float v = acc[mi][nj][rr] + bv;
              if (ACT == 1) v = v / (1.f + __expf(-v));
              else if (ACT == 2) v = 0.5f * v * (1.f + erff(v * 0.70710678118f));
              Ep[(mi * 16 + lrow + rr) * 256 + colb + nj * 16] = v;
            }
        }
      }
      __syncthreads();
#pragma unroll
      for (int it = 0; it < 16; ++it) {
        int idx = it * 512 + tid;
        int row = idx >> 6, c4 = idx & 63;
        size_t g = (size_t)(bm + ch * 128 + row) * ldc + bn + c4 * 4;
        float4 sv = ((const float4*)Ep)[idx];
        if (OUTM == 1) {
          float4 od = *(const float4*)(Cf + g);
          sv.x += od.x; sv.y += od.y; sv.z += od.z; sv.w += od.w;
        }
        *(float4*)(Cf + g) = sv;
      }
      __syncthreads();
    }
  }
}

// ---------- LayerNorm over D=512: fp32 in, fp32 w/b, bf16 out ----------
__global__ __launch_bounds__(256)
void k_layernorm(const float* __restrict__ X, const float* __restrict__ w,
                 const float* __restrict__ b, u16* __restrict__ Y) {
  int row = blockIdx.x, tid = threadIdx.x;
  const float* x = X + (size_t)row * 512;
  float v0 = x[tid], v1 = x[tid + 256];
  __shared__ float red[4];
  float s = v0 + v1;
  for (int o = 32; o; o >>= 1) s += __shfl_down(s, o, 64);
  if ((tid & 63) == 0) red[tid >> 6] = s;
  __syncthreads();
  if (tid == 0) red[0] = (red[0] + red[1] + red[2] + red[3]) * (1.f / 512.f);
  __syncthreads();
  float mean = red[0];
  __syncthreads();
  float d0 = v0 - mean, d1 = v1 - mean;
  float q = d0 * d0 + d1 * d1;
  for (int o = 32; o; o >>= 1) q += __shfl_down(q, o, 64);
  if ((tid & 63) == 0) red[tid >> 6] = q;
  __syncthreads();
  if (tid == 0) red[0] = (red[0] + red[1] + red[2] + red[3]) * (1.f / 512.f);
  __syncthreads();
  float rstd = rsqrtf(red[0] + 1e-5f);
  size_t o0 = (size_t)row * 512 + tid;
  Y[o0] = f2bf(d0 * rstd * w[tid] + b[tid]);
  Y[o0 + 256] = f2bf(d1 * rstd * w[tid + 256] + b[tid + 256]);
}

// ---------- condition input gather (fp32 tables -> bf16, padded to 320) ----------
__global__ void k_cond_gather(const int* __restrict__ note_id, const int* __restrict__ phon_id,
                              const int* __restrict__ slur, const int* __restrict__ pp,
                              const float* __restrict__ note_emb, const float* __restrict__ phon_emb,
                              const float* __restrict__ slur_emb, const float* __restrict__ pp_emb,
                              u16* __restrict__ out) {
  int bt = blockIdx.x, t = threadIdx.x;  // block = 320
  u16 v = 0;
  if (t < 128) v = f2bf(note_emb[note_id[bt] * 128 + t]);
  else if (t < 256) v = f2bf(phon_emb[phon_id[bt] * 128 + (t - 128)]);
  else if (t < 272) {
    int sv = slur[bt]; sv = sv < 0 ? 0 : (sv > 1 ? 1 : sv);
    v = f2bf(slur_emb[sv * 16 + (t - 256)]);
  } else if (t < 304) v = f2bf(pp_emb[pp[bt] * 32 + (t - 272)]);
  out[bt * 320 + t] = v;
}

// pad+cast cond_w1 [256,304] fp32 -> [256,320] bf16
__global__ void k_pad_w(const float* __restrict__ w, u16* __restrict__ out) {
  int n = blockIdx.x, t = threadIdx.x;  // grid 256, block 320
  out[n * 320 + t] = (t < 304) ? f2bf(w[n * 304 + t]) : (u16)0;
}

// gather temb(bf16)[codes[...,0]] -> f_emb [32768,256] (uint4 = 8 bf16)
__global__ void k_femb(const int* __restrict__ codes, const uint4* __restrict__ emb,
                       uint4* __restrict__ out) {
  int i = blockIdx.x * 256 + threadIdx.x;  // < 32768*32
  int m = i >> 5, c = i & 31;
  out[i] = emb[(size_t)codes[m * 2] * 32 + c];
}

// pooled[bt,c] = mean_s f_emb[bt*64+s, c]
__global__ void k_pool(const u16* __restrict__ femb, u16* __restrict__ pooled) {
  int bt = blockIdx.x, c = threadIdx.x;  // block 256
  float s = 0.f;
  for (int j = 0; j < 64; ++j) s += bf2f(femb[((size_t)bt * 64 + j) * 256 + c]);
  pooled[bt * 256 + c] = f2bf(s * (1.f / 64.f));
}

// step_in[bt] = [cond[bt] | (t==0 ? bos(fp32) : prevo[bt-1])]
__global__ void k_stepin(const u16* __restrict__ cond, const u16* __restrict__ prevo,
                         const float* __restrict__ bosf, u16* __restrict__ out) {
  int bt = blockIdx.x, t = threadIdx.x;  // block 512
  u16 v;
  if (t < 256) v = cond[bt * 256 + t];
  else {
    int tt = bt & 127;
    v = (tt == 0) ? f2bf(bosf[t - 256]) : prevo[(bt - 1) * 256 + (t - 256)];
  }
  out[bt * 512 + t] = v;
}

// ---------- ctx attention: one wave per (b,h,t), window 32 causal ----------
__global__ __launch_bounds__(64)
void k_ctx_attn(const u16* __restrict__ qkv, u16* __restrict__ out) {
  int t = blockIdx.x, h = blockIdx.y, b = blockIdx.z;
  int lane = threadIdx.x;
  int bt = b * 128 + t;
  float qd = bf2f(qkv[(size_t)bt * 1536 + h * 64 + lane]) * 0.125f;
  int klo = t - 31; if (klo < 0) klo = 0;
  int n = t - klo + 1;
  __shared__ float sc[32];
  for (int i = 0; i < n; ++i) {
    float p = qd * bf2f(qkv[((size_t)(b * 128 + klo + i)) * 1536 + 512 + h * 64 + lane]);
    for (int o = 32; o; o >>= 1) p += __shfl_xor(p, o, 64);
    if (lane == 0) sc[i] = p;
  }
  __syncthreads();
  float mx = -1e30f;
  for (int i = 0; i < n; ++i) mx = fmaxf(mx, sc[i]);
  float den = 0.f, acc = 0.f;
  for (int i = 0; i < n; ++i) {
    float p = __expf(sc[i] - mx);
    den += p;
    acc += p * bf2f(qkv[((size_t)(b * 128 + klo + i)) * 1536 + 1024 + h * 64 + lane]);
  }
  out[(size_t)bt * 512 + h * 64 + lane] = f2bf(acc / den);
}

// ---------- audio attention, MFMA: one wave per (seq,head); S=64, D=64, causal ----------
// NOTE: the two waves of a block are fully independent (all LDS buffers are
// [wave]-indexed; write->read is wave-local and DS ops are in-order per wave),
// so there is NO __syncthreads — removing it de-convoys the waves.
__global__ __launch_bounds__(128)
void k_aud_attn_mfma(const u16* __restrict__ qkv, u16* __restrict__ out) {
  constexpr int LP = 66;
  __shared__ u16 Pl[2][64 * LP];
  __shared__ u16 Vt[2][64 * LP];
  const int wave = threadIdx.x >> 6, lane = threadIdx.x & 63;
  const int id = blockIdx.x * 2 + wave;       // 0..4095
  const int seq = id >> 3, h = id & 7;
  const u16* Qb = qkv + (size_t)seq * 64 * 1536 + h * 64;
  const u16* Kb = Qb + 512;
  const u16* Vb = Qb + 1024;
  u16* Plw = Pl[wave];
  u16* Vtw = Vt[wave];
  const int fr = lane & 15, fq = (lane >> 4) * 8;

#pragma unroll
  for (int t = 0; t < 8; ++t) {
    int vr = (lane >> 3) + 8 * t, vc = (lane & 7) * 8;
    uint4 vv = *(const uint4*)(Vb + (size_t)vr * 1536 + vc);
    Vtw[(vc + 0) * LP + vr] = (u16)(vv.x & 0xffff);
    Vtw[(vc + 1) * LP + vr] = (u16)(vv.x >> 16);
    Vtw[(vc + 2) * LP + vr] = (u16)(vv.y & 0xffff);
    Vtw[(vc + 3) * LP + vr] = (u16)(vv.y >> 16);
    Vtw[(vc + 4) * LP + vr] = (u16)(vv.z & 0xffff);
    Vtw[(vc + 5) * LP + vr] = (u16)(vv.z >> 16);
    Vtw[(vc + 6) * LP + vr] = (u16)(vv.w & 0xffff);
    Vtw[(vc + 7) * LP + vr] = (u16)(vv.w >> 16);
  }

  bf16x8 aq[4][2], bk[4][2];
#pragma unroll
  for (int i = 0; i < 4; ++i)
#pragma unroll
    for (int c = 0; c < 2; ++c) {
      aq[i][c] = *(const bf16x8*)(Qb + (size_t)(i * 16 + fr) * 1536 + fq + 32 * c);
      bk[i][c] = *(const bf16x8*)(Kb + (size_t)(i * 16 + fr) * 1536 + fq + 32 * c);
    }
  f32x4 s[4][4];
#pragma unroll
  for (int i = 0; i < 4; ++i)
#pragma unroll
    for (int j = 0; j < 4; ++j) s[i][j] = (f32x4){0.f, 0.f, 0.f, 0.f};
#pragma unroll
  for (int c = 0; c < 2; ++c)
#pragma unroll
    for (int i = 0; i < 4; ++i)
#pragma unroll
      for (int j = 0; j < 4; ++j)
        s[i][j] = __builtin_amdgcn_mfma_f32_16x16x32_bf16(aq[i][c], bk[j][c], s[i][j], 0, 0, 0);

  const int qr = (lane >> 4) * 4;
#pragma unroll
  for (int i = 0; i < 4; ++i) {
#pragma unroll
    for (int r = 0; r < 4; ++r) {
      int row = 16 * i + qr + r;
      float mx = -1e30f;
      float vj[4];
#pragma unroll
      for (int j = 0; j < 4; ++j) {
        float v = s[i][j][r] * 0.125f;
        if (16 * j + fr > row) v = -1e30f;   // causal
        vj[j] = v;
        mx = fmaxf(mx, v);
      }
      for (int o = 8; o; o >>= 1) mx = fmaxf(mx, __shfl_xor(mx, o, 64));
      float den = 0.f;
#pragma unroll
      for (int j = 0; j < 4; ++j) { vj[j] = __expf(vj[j] - mx); den += vj[j]; }
      for (int o = 8; o; o >>= 1) den += __shfl_xor(den, o, 64);
      float inv = 1.f / den;
#pragma unroll
      for (int j = 0; j < 4; ++j)
        Plw[row * LP + 16 * j + fr] = f2bf(vj[j] * inv);
    }
  }
  // (no __syncthreads: wave-local DS ordering suffices)

  f32x4 o4[4][4];
#pragma unroll
  for (int i = 0; i < 4; ++i)
#pragma unroll
    for (int j = 0; j < 4; ++j) o4[i][j] = (f32x4){0.f, 0.f, 0.f, 0.f};
#pragma unroll
  for (int c = 0; c < 2; ++c) {
    bf16x8 ap[4], bv[4];
#pragma unroll
    for (int i = 0; i < 4; ++i)
      ap[i] = *(const bf16x8*)&Plw[(16 * i + fr) * LP + fq + 32 * c];
#pragma unroll
    for (int j = 0; j < 4; ++j)
      bv[j] = *(const bf16x8*)&Vtw[(16 * j + fr) * LP + fq + 32 * c];
#pragma unroll
    for (int i = 0; i < 4; ++i)
#pragma unroll
      for (int j = 0; j < 4; ++j)
        o4[i][j] = __builtin_amdgcn_mfma_f32_16x16x32_bf16(ap[i], bv[j], o4[i][j], 0, 0, 0);
  }
#pragma unroll
  for (int i = 0; i < 4; ++i)
#pragma unroll
    for (int r = 0; r < 4; ++r) {
      int row = 16 * i + qr + r;
      u16* ob = out + ((size_t)seq * 64 + row) * 512 + h * 64;
#pragma unroll
      for (int j = 0; j < 4; ++j) ob[16 * j + fr] = f2bf(o4[i][j][r]);
    }
}

// a[row,d] = (s==0 ? bos(fp32) : tok[row-1](bf16)) + frame_pos[s](fp32) + h[bt](fp32)
__global__ void k_abuild(const uint4* __restrict__ tok, const float4* __restrict__ bosf,
                         const float4* __restrict__ fpos, const float4* __restrict__ hstep,
                         float4* __restrict__ a) {
  size_t i = (size_t)blockIdx.x * 256 + threadIdx.x;  // < 32768*64
  int d8 = (int)(i & 63);
  size_t row = i >> 6;
  int s = (int)(row & 63);
  size_t bt = row >> 6;
  float t0, t1, t2, t3, t4, t5, t6, t7;
  if (s == 0) {
    float4 b0 = bosf[d8 * 2], b1 = bosf[d8 * 2 + 1];
    t0 = b0.x; t1 = b0.y; t2 = b0.z; t3 = b0.w;
    t4 = b1.x; t5 = b1.y; t6 = b1.z; t7 = b1.w;
  } else {
    uint4 tv = tok[(row - 1) * 64 + d8];
    t0 = lo16(tv.x); t1 = hi16(tv.x); t2 = lo16(tv.y); t3 = hi16(tv.y);
    t4 = lo16(tv.z); t5 = hi16(tv.z); t6 = lo16(tv.w); t7 = hi16(tv.w);
  }
  float4 f0 = fpos[(size_t)s * 128 + d8 * 2], f1 = fpos[(size_t)s * 128 + d8 * 2 + 1];
  float4 h0 = hstep[bt * 128 + d8 * 2], h1 = hstep[bt * 128 + d8 * 2 + 1];
  float4 o0, o1;
  o0.x = t0 + f0.x + h0.x; o0.y = t1 + f0.y + h0.y;
  o0.z = t2 + f0.z + h0.z; o0.w = t3 + f0.w + h0.w;
  o1.x = t4 + f1.x + h1.x; o1.y = t5 + f1.y + h1.y;
  o1.z = t6 + f1.z + h1.z; o1.w = t7 + f1.w + h1.w;
  a[i * 2] = o0; a[i * 2 + 1] = o1;
}

// ---------- host side ----------
template<int ACT, int OUTM>
static inline void gemmS(const u16* A, const u16* W, const float* bias, void* C,
                         int M, int N, int K, int ldc, hipStream_t s) {
  gemm_mfma64<ACT, OUTM><<<dim3(N / 64, M / 64), 256, 0, s>>>(A, W, bias, C, M, N, K, ldc);
}

template<int ACT, int OUTM>
static inline void gemmBig(const u16* A, const u16* W, const float* bias, void* C,
                           int M, int N, int K, int ldc, hipStream_t s) {
  gemm_mfma256<ACT, OUTM, 0><<<dim3(N / 256, M / 256), 512, 0, s>>>(A, nullptr, W, bias, C, M, N, K, ldc);
}

template<int ACT, int OUTM>
static inline void gemmBigSplit(const u16* A, const u16* A2, const u16* W, const float* bias,
                                void* C, int M, int N, int K, int ldc, hipStream_t s) {
  gemm_mfma256<ACT, OUTM, 1><<<dim3(N / 256, M / 256), 512, 0, s>>>(A, A2, W, bias, C, M, N, K, ldc);
}

static inline void cast_bf16(const float* x, u16* y, size_t n, hipStream_t s) {
  int n8 = (int)(n / 8);
  k_cast8<<<(n8 + 255) / 256, 256, 0, s>>>((const float4*)x, (uint4*)y, n8);
}

extern "C" void kernel_launch(void* const* d_in, const int* in_sizes, int n_in,
                              void* d_out, int out_size, void* d_ws, size_t ws_size,
                              hipStream_t stream) {
  const int* codes    = (const int*)d_in[0];
  const int* note_id  = (const int*)d_in[1];
  const int* phon_id  = (const int*)d_in[2];
  const int* slur     = (const int*)d_in[3];
  const int* pprog    = (const int*)d_in[4];
  const float* note_emb = (const float*)d_in[5];
  const float* phon_emb = (const float*)d_in[6];
  const float* slur_emb = (const float*)d_in[7];
  const float* pp_emb   = (const float*)d_in[8];
  const float* cond_w1  = (const float*)d_in[9];
  const float* cond_b1  = (const float*)d_in[10];
  const float* cond_w2  = (const float*)d_in[11];
  const float* cond_b2  = (const float*)d_in[12];
  const float* tok_emb  = (const float*)d_in[13];
  const float* prev_w1  = (const float*)d_in[14];
  const float* prev_b1  = (const float*)d_in[15];
  const float* prev_w2  = (const float*)d_in[16];
  const float* prev_b2  = (const float*)d_in[17];
  const float* bos_step = (const float*)d_in[18];
  const float* step_w1  = (const float*)d_in[19];
  const float* step_b1  = (const float*)d_in[20];
  const float* step_w2  = (const float*)d_in[21];
  const float* step_b2  = (const float*)d_in[22];
  const float* audio_in_w = (const float*)d_in[23];
  const float* audio_in_b = (const float*)d_in[24];
  const float* audio_bos  = (const float*)d_in[25];
  const float* frame_pos  = (const float*)d_in[26];
  const float* first_w  = (const float*)d_in[27];
  const float* first_b  = (const float*)d_in[28];
  const float* resc_w1  = (const float*)d_in[29];
  const float* resc_b1  = (const float*)d_in[30];
  const float* resc_w2  = (const float*)d_in[31];
  const float* resc_b2  = (const float*)d_in[32];
  const float* res_w    = (const float*)d_in[33];
  const float* res_b    = (const float*)d_in[34];
  const float* ctx_w[12]; for (int i = 0; i < 12; ++i) ctx_w[i] = (const float*)d_in[35 + i];
  const float* aud_w[12]; for (int i = 0; i < 12; ++i) aud_w[i] = (const float*)d_in[47 + i];

  // workspace layout (deterministic every call)
  char* p = (char*)d_ws;
  auto alloc = [&](size_t b) { char* r = p; p += (b + 255) & ~(size_t)255; return r; };
  float* A_res = (float*)alloc(32768ull * 512 * 4);   // audio residual stream (fp32)
  u16* T_tok  = (u16*)alloc(32768ull * 512 * 2);      // tok (later reused for rh)
  u16* LNb    = (u16*)alloc(32768ull * 512 * 2);      // ln out / ah bf16
  u16* AOb    = (u16*)alloc(32768ull * 512 * 2);      // attn out / resc mid
  u16* QF     = (u16*)alloc(32768ull * 2048 * 2);     // qkv / ffn-mid
  u16* f_emb  = (u16*)alloc(32768ull * 256 * 2);
  u16* temb   = (u16*)alloc(1024ull * 256 * 2);       // token_emb bf16
  u16* cond_in = (u16*)alloc(512ull * 320 * 2);
  u16* cw1p   = (u16*)alloc(256ull * 320 * 2);
  u16* cw2    = (u16*)alloc(256ull * 256 * 2);
  u16* pw1    = (u16*)alloc(256ull * 256 * 2);
  u16* pw2    = (u16*)alloc(256ull * 256 * 2);
  u16* sw1    = (u16*)alloc(512ull * 512 * 2);
  u16* sw2    = (u16*)alloc(512ull * 512 * 2);
  u16* ainw   = (u16*)alloc(512ull * 256 * 2);
  u16* fw     = (u16*)alloc(1024ull * 512 * 2);
  u16* rw1    = (u16*)alloc(512ull * 1024 * 2);
  u16* rw2    = (u16*)alloc(512ull * 512 * 2);
  u16* resw   = (u16*)alloc(1024ull * 512 * 2);
  u16* cxin   = (u16*)alloc(4ull * 1536 * 512 * 2);
  u16* cxout  = (u16*)alloc(4ull * 512 * 512 * 2);
  u16* cxf1   = (u16*)alloc(4ull * 2048 * 512 * 2);
  u16* cxf2   = (u16*)alloc(4ull * 512 * 2048 * 2);
  u16* adin   = (u16*)alloc(6ull * 1536 * 512 * 2);
  u16* adout  = (u16*)alloc(6ull * 512 * 512 * 2);
  u16* adf1   = (u16*)alloc(6ull * 2048 * 512 * 2);
  u16* adf2   = (u16*)alloc(6ull * 512 * 2048 * 2);
  u16* cond_h = (u16*)alloc(512ull * 256 * 2);
  u16* condv  = (u16*)alloc(512ull * 256 * 2);
  u16* pooled = (u16*)alloc(512ull * 256 * 2);
  u16* prevh  = (u16*)alloc(512ull * 256 * 2);
  u16* prevo  = (u16*)alloc(512ull * 256 * 2);
  u16* stepin = (u16*)alloc(512ull * 512 * 2);
  u16* hmid   = (u16*)alloc(512ull * 512 * 2);
  float* hstep = (float*)alloc(512ull * 512 * 4);     // ctx residual stream (fp32)

  // ---- weight fp32 -> bf16 conversions ----
  k_pad_w<<<256, 320, 0, stream>>>(cond_w1, cw1p);
  cast_bf16(cond_w2, cw2, 256ull * 256, stream);
  cast_bf16(prev_w1, pw1, 256ull * 256, stream);
  cast_bf16(prev_w2, pw2, 256ull * 256, stream);
  cast_bf16(step_w1, sw1, 512ull * 512, stream);
  cast_bf16(step_w2, sw2, 512ull * 512, stream);
  cast_bf16(tok_emb, temb, 1024ull * 256, stream);
  cast_bf16(audio_in_w, ainw, 512ull * 256, stream);
  cast_bf16(first_w, fw, 1024ull * 512, stream);
  cast_bf16(resc_w1, rw1, 512ull * 1024, stream);
  cast_bf16(resc_w2, rw2, 512ull * 512, stream);
  cast_bf16(res_w, resw, 1024ull * 512, stream);
  cast_bf16(ctx_w[2], cxin, 4ull * 1536 * 512, stream);
  cast_bf16(ctx_w[4], cxout, 4ull * 512 * 512, stream);
  cast_bf16(ctx_w[8], cxf1, 4ull * 2048 * 512, stream);
  cast_bf16(ctx_w[10], cxf2, 4ull * 512 * 2048, stream);
  cast_bf16(aud_w[2], adin, 6ull * 1536 * 512, stream);
  cast_bf16(aud_w[4], adout, 6ull * 512 * 512, stream);
  cast_bf16(aud_w[8], adf1, 6ull * 2048 * 512, stream);
  cast_bf16(aud_w[10], adf2, 6ull * 512 * 2048, stream);

  // ---- cond / prev / step (M=512: 64^2-tile GEMMs for block-parallelism) ----
  k_cond_gather<<<512, 320, 0, stream>>>(note_id, phon_id, slur, pprog,
                                         note_emb, phon_emb, slur_emb, pp_emb, cond_in);
  k_femb<<<4096, 256, 0, stream>>>(codes, (const uint4*)temb, (uint4*)f_emb);
  k_pool<<<512, 256, 0, stream>>>(f_emb, pooled);
  gemmS<1, 0>(cond_in, cw1p, cond_b1, cond_h, 512, 256, 320, 256, stream);
  gemmS<0, 0>(cond_h, cw2, cond_b2, condv, 512, 256, 256, 256, stream);
  gemmS<1, 0>(pooled, pw1, prev_b1, prevh, 512, 256, 256, 256, stream);
  gemmS<0, 0>(prevh, pw2, prev_b2, prevo, 512, 256, 256, 256, stream);
  k_stepin<<<512, 512, 0, stream>>>(condv, prevo, bos_step, stepin);
  gemmS<1, 0>(stepin, sw1, step_b1, hmid, 512, 512, 512, 512, stream);
  gemmS<0, 2>(hmid, sw2, step_b2, hstep, 512, 512, 512, 512, stream);

  // ---- context transformer (T=128, win=32) ----
  for (int l = 0; l < 4; ++l) {
    k_layernorm<<<512, 256, 0, stream>>>(hstep, ctx_w[0] + l * 512, ctx_w[1] + l * 512, LNb);
    gemmS<0, 0>(LNb, cxin + (size_t)l * 1536 * 512, ctx_w[3] + l * 1536, QF, 512, 1536, 512, 1536, stream);
    k_ctx_attn<<<dim3(128, 8, 4), 64, 0, stream>>>(QF, AOb);
    gemmS<0, 1>(AOb, cxout + (size_t)l * 512 * 512, ctx_w[5] + l * 512, hstep, 512, 512, 512, 512, stream);
    k_layernorm<<<512, 256, 0, stream>>>(hstep, ctx_w[6] + l * 512, ctx_w[7] + l * 512, LNb);
    gemmS<2, 0>(LNb, cxf1 + (size_t)l * 2048 * 512, ctx_w[9] + l * 2048, QF, 512, 2048, 512, 2048, stream);
    gemmS<0, 1>(QF, cxf2 + (size_t)l * 512 * 2048, ctx_w[11] + l * 512, hstep, 512, 512, 2048, 512, stream);
  }

  // ---- audio decoder ----
  gemmBig<0, 0>(f_emb, ainw, audio_in_b, T_tok, 32768, 512, 256, 512, stream);
  k_abuild<<<8192, 256, 0, stream>>>((const uint4*)T_tok, (const float4*)audio_bos,
                                     (const float4*)frame_pos, (const float4*)hstep, (float4*)A_res);
  for (int l = 0; l < 6; ++l) {
    k_layernorm<<<32768, 256, 0, stream>>>(A_res, aud_w[0] + l * 512, aud_w[1] + l * 512, LNb);
    gemmBig<0, 0>(LNb, adin + (size_t)l * 1536 * 512, aud_w[3] + l * 1536, QF, 32768, 1536, 512, 1536, stream);
    k_aud_attn_mfma<<<2048, 128, 0, stream>>>(QF, AOb);
    gemmBig<0, 1>(AOb, adout + (size_t)l * 512 * 512, aud_w[5] + l * 512, A_res, 32768, 512, 512, 512, stream);
    k_layernorm<<<32768, 256, 0, stream>>>(A_res, aud_w[6] + l * 512, aud_w[7] + l * 512, LNb);
    gemmBig<2, 0>(LNb, adf1 + (size_t)l * 2048 * 512, aud_w[9] + l * 2048, QF, 32768, 2048, 512, 2048, stream);
    gemmBig<0, 1>(QF, adf2 + (size_t)l * 512 * 2048, aud_w[11] + l * 512, A_res, 32768, 512, 2048, 512, stream);
  }

  // ---- heads (fp32 output) ----
  {
    int n8 = 32768 * 512 / 8;
    k_cast8<<<(n8 + 255) / 256, 256, 0, stream>>>((const float4*)A_res, (uint4*)LNb, n8);
  }
  gemmBig<0, 2>(LNb, fw, first_b, (float*)d_out, 32768, 1024, 512, 2048, stream);            // k=0 slot
  // rw1 reads the virtual concat [LNb | T_tok] directly (k_cat fused into staging);
  // T_tok is only overwritten by rw2 AFTER rw1 completes (same stream).
  gemmBigSplit<1, 0>(LNb, T_tok, rw1, resc_b1, AOb, 32768, 512, 1024, 512, stream);
  gemmBig<0, 0>(AOb, rw2, resc_b2, T_tok, 32768, 512, 512, 512, stream);                     // rh
  gemmBig<0, 2>(T_tok, resw, res_b, (float*)d_out + 1024, 32768, 1024, 512, 2048, stream);   // k=1 slot
}